// Round 1
// baseline (4392.236 us; speedup 1.0000x reference)
//
#include <hip/hip_runtime.h>
#include <math.h>

#define N_NODES 10000
#define D_IN    512
#define D_H1    512
#define D_H2    256
#define N_EDGE  320000
#define NK      31
#define NSLICE  4

// ---------------------------------------------------------------------------
// GEMM: C[M,N] = act(A[M,K] @ B[K,N] + bias), 64x64 tile, 256 thr, 4x4/thread
// ---------------------------------------------------------------------------
__global__ __launch_bounds__(256) void gemm_bias(
    const float* __restrict__ A, const float* __restrict__ B,
    const float* __restrict__ bias, float* __restrict__ C,
    int M, int N, int K, int do_relu)
{
    __shared__ __align__(16) float As[16][68];
    __shared__ __align__(16) float Bs[16][68];
    const int bm = blockIdx.y * 64, bn = blockIdx.x * 64;
    const int tid = threadIdx.x;
    const int tx = tid & 15, ty = tid >> 4;
    const int arow = tid >> 2, akk = (tid & 3) << 2;
    const int bkk = tid >> 4, bnn = (tid & 15) << 2;
    const bool aval = (bm + arow) < M;
    const float* Ap = A + (size_t)(bm + arow) * K;

    float acc[4][4];
    #pragma unroll
    for (int i = 0; i < 4; ++i)
        #pragma unroll
        for (int j = 0; j < 4; ++j) acc[i][j] = 0.f;

    for (int k0 = 0; k0 < K; k0 += 16) {
        float4 av = make_float4(0.f, 0.f, 0.f, 0.f);
        if (aval) av = *(const float4*)(Ap + k0 + akk);
        float4 bv = *(const float4*)(B + (size_t)(k0 + bkk) * N + bn + bnn);
        As[akk + 0][arow] = av.x; As[akk + 1][arow] = av.y;
        As[akk + 2][arow] = av.z; As[akk + 3][arow] = av.w;
        *(float4*)&Bs[bkk][bnn] = bv;
        __syncthreads();
        #pragma unroll
        for (int kk = 0; kk < 16; ++kk) {
            float a[4], b[4];
            *(float4*)a = *(const float4*)&As[kk][ty << 2];
            *(float4*)b = *(const float4*)&Bs[kk][tx << 2];
            #pragma unroll
            for (int i = 0; i < 4; ++i)
                #pragma unroll
                for (int j = 0; j < 4; ++j) acc[i][j] = fmaf(a[i], b[j], acc[i][j]);
        }
        __syncthreads();
    }

    float4 bb = *(const float4*)(bias + bn + (tx << 2));
    float bias4[4] = {bb.x, bb.y, bb.z, bb.w};
    #pragma unroll
    for (int i = 0; i < 4; ++i) {
        int row = bm + (ty << 2) + i;
        if (row < M) {
            float out[4];
            #pragma unroll
            for (int j = 0; j < 4; ++j) {
                float v = acc[i][j] + bias4[j];
                if (do_relu) v = fmaxf(v, 0.f);
                out[j] = v;
            }
            *(float4*)(C + (size_t)row * N + bn + (tx << 2)) = *(float4*)out;
        }
    }
}

// ---------------------------------------------------------------------------
// CSR build helpers
// ---------------------------------------------------------------------------
__global__ void hist_kernel(const int* __restrict__ idx, int* __restrict__ cnt, int n)
{
    int i = blockIdx.x * 256 + threadIdx.x;
    if (i < n) atomicAdd(&cnt[idx[i]], 1);
}

__global__ __launch_bounds__(256) void scan_kernel(
    const int* __restrict__ cnt, int* __restrict__ offs, int* __restrict__ nxt, int n)
{
    __shared__ int ssum[256];
    int t = threadIdx.x;
    int per = (n + 255) >> 8;
    int lo = t * per, hi = min(lo + per, n);
    int s = 0;
    for (int i = lo; i < hi; ++i) s += cnt[i];
    ssum[t] = s;
    __syncthreads();
    if (t == 0) {
        int run = 0;
        for (int i = 0; i < 256; ++i) { int x = ssum[i]; ssum[i] = run; run += x; }
    }
    __syncthreads();
    int run = ssum[t];
    for (int i = lo; i < hi; ++i) { offs[i] = run; nxt[i] = run; run += cnt[i]; }
}

__global__ void scatter_adj(const int* __restrict__ rows, const int* __restrict__ cols,
                            const float* __restrict__ vals, int* __restrict__ nxt,
                            int* __restrict__ ccol, float* __restrict__ cval, int n)
{
    int e = blockIdx.x * 256 + threadIdx.x;
    if (e >= n) return;
    int p = atomicAdd(&nxt[rows[e]], 1);
    ccol[p] = cols[e];
    cval[p] = vals[e];
}

__global__ void scatter_knn(const int* __restrict__ tc, int* __restrict__ nxt,
                            int* __restrict__ eid, int n)
{
    int e = blockIdx.x * 256 + threadIdx.x;
    if (e >= n) return;
    int p = atomicAdd(&nxt[tc[e]], 1);
    eid[p] = e;
}

// ---------------------------------------------------------------------------
// CSR spmm: out[row,:] = sum_e val_e * H[col_e,:]   (one wave per row, D=256)
// ---------------------------------------------------------------------------
__global__ __launch_bounds__(256) void spmm_csr(
    const int* __restrict__ offs, const int* __restrict__ cnt,
    const int* __restrict__ cols, const float* __restrict__ vals,
    const float* __restrict__ H, float* __restrict__ out, int n)
{
    int row = blockIdx.x * 4 + (threadIdx.x >> 6);
    if (row >= n) return;
    int lane = threadIdx.x & 63;
    int st = offs[row], en = st + cnt[row];
    float a0 = 0.f, a1 = 0.f, a2 = 0.f, a3 = 0.f;
    for (int p = st; p < en; ++p) {
        int c = cols[p];
        float v = vals[p];
        float4 h = *(const float4*)(H + (size_t)c * D_H2 + (lane << 2));
        a0 = fmaf(v, h.x, a0); a1 = fmaf(v, h.y, a1);
        a2 = fmaf(v, h.z, a2); a3 = fmaf(v, h.w, a3);
    }
    float4 o = make_float4(a0, a1, a2, a3);
    *(float4*)(out + (size_t)row * D_H2 + (lane << 2)) = o;
}

// ---------------------------------------------------------------------------
// Row L2-normalize: Xn = ha / max(||ha||, 1e-12)
// ---------------------------------------------------------------------------
__global__ __launch_bounds__(256) void rownorm(
    const float* __restrict__ ha, float* __restrict__ xn, int n)
{
    int row = blockIdx.x * 4 + (threadIdx.x >> 6);
    if (row >= n) return;
    int lane = threadIdx.x & 63;
    float4 h = *(const float4*)(ha + (size_t)row * D_H2 + (lane << 2));
    float s = h.x * h.x + h.y * h.y + h.z * h.z + h.w * h.w;
    #pragma unroll
    for (int m = 1; m < 64; m <<= 1) s += __shfl_xor(s, m);
    float inv = 1.f / fmaxf(sqrtf(s), 1e-12f);
    h.x *= inv; h.y *= inv; h.z *= inv; h.w *= inv;
    *(float4*)(xn + (size_t)row * D_H2 + (lane << 2)) = h;
}

// ---------------------------------------------------------------------------
// Fused sim-GEMM + per-row online top-31.
// Block: 32 rows x [jbeg,jend) col slice.  256 thr: ty(0..7)->4 rows, tx(0..31)->4 cols
// ---------------------------------------------------------------------------
__global__ __launch_bounds__(256) void simtopk(
    const float* __restrict__ Xn, float* __restrict__ ptv, int* __restrict__ ptc, int n)
{
    __shared__ __align__(16) float Xi[256][36];   // transposed i-tile
    __shared__ __align__(16) float Xj[32][132];   // transposed j k-slice
    __shared__ float sv[32][133];                 // chunk scores
    __shared__ float stopv[32][NK];
    __shared__ int   stopc[32][NK];
    __shared__ float sthr[32];
    __shared__ int   scnt[32], smin[32];

    const int i0 = blockIdx.x * 32;
    const int slice = blockIdx.y;
    const int jspan = n / NSLICE;
    const int jbeg = slice * jspan, jend = jbeg + jspan;
    const int tid = threadIdx.x;
    const int tx = tid & 31, ty = tid >> 5;

    #pragma unroll
    for (int it = 0; it < 8; ++it) {
        int idx = tid + it * 256;
        int r = idx >> 6, k4 = (idx & 63) << 2;
        float4 v = make_float4(0.f, 0.f, 0.f, 0.f);
        if (i0 + r < n) v = *(const float4*)(Xn + (size_t)(i0 + r) * 256 + k4);
        Xi[k4 + 0][r] = v.x; Xi[k4 + 1][r] = v.y;
        Xi[k4 + 2][r] = v.z; Xi[k4 + 3][r] = v.w;
    }
    if (tid < 32) { sthr[tid] = -1e30f; scnt[tid] = 0; smin[tid] = 0; }
    __syncthreads();

    for (int j0 = jbeg; j0 < jend; j0 += 128) {
        const int ncol = min(128, jend - j0);
        float acc[4][4];
        #pragma unroll
        for (int i = 0; i < 4; ++i)
            #pragma unroll
            for (int j = 0; j < 4; ++j) acc[i][j] = 0.f;

        for (int k0 = 0; k0 < 256; k0 += 32) {
            #pragma unroll
            for (int it = 0; it < 4; ++it) {
                int idx = tid + it * 256;
                int c = idx >> 3, k4 = (idx & 7) << 2;
                float4 v = make_float4(0.f, 0.f, 0.f, 0.f);
                if (c < ncol) v = *(const float4*)(Xn + (size_t)(j0 + c) * 256 + k0 + k4);
                Xj[k4 + 0][c] = v.x; Xj[k4 + 1][c] = v.y;
                Xj[k4 + 2][c] = v.z; Xj[k4 + 3][c] = v.w;
            }
            __syncthreads();
            #pragma unroll
            for (int kk = 0; kk < 32; ++kk) {
                float a[4], b[4];
                *(float4*)a = *(const float4*)&Xi[k0 + kk][ty << 2];
                *(float4*)b = *(const float4*)&Xj[kk][tx << 2];
                #pragma unroll
                for (int i = 0; i < 4; ++i)
                    #pragma unroll
                    for (int j = 0; j < 4; ++j) acc[i][j] = fmaf(a[i], b[j], acc[i][j]);
            }
            __syncthreads();
        }

        #pragma unroll
        for (int i = 0; i < 4; ++i)
            #pragma unroll
            for (int j = 0; j < 4; ++j)
                sv[(ty << 2) + i][(tx << 2) + j] =
                    ((tx << 2) + j < ncol) ? acc[i][j] : -1e30f;
        __syncthreads();

        if (tid < 32) {
            float lthr = sthr[tid]; int lcnt = scnt[tid]; int lmin = smin[tid];
            for (int c = 0; c < ncol; ++c) {
                float v = sv[tid][c];
                if (lcnt < NK) {
                    stopv[tid][lcnt] = v; stopc[tid][lcnt] = j0 + c; lcnt++;
                    if (lcnt == NK) {
                        lmin = 0; lthr = stopv[tid][0];
                        for (int q = 1; q < NK; ++q) {
                            float x = stopv[tid][q];
                            if (x < lthr) { lthr = x; lmin = q; }
                        }
                    }
                } else if (v > lthr) {
                    stopv[tid][lmin] = v; stopc[tid][lmin] = j0 + c;
                    lmin = 0; lthr = stopv[tid][0];
                    for (int q = 1; q < NK; ++q) {
                        float x = stopv[tid][q];
                        if (x < lthr) { lthr = x; lmin = q; }
                    }
                }
            }
            sthr[tid] = lthr; scnt[tid] = lcnt; smin[tid] = lmin;
        }
        __syncthreads();
    }

    #pragma unroll
    for (int it = 0; it < 4; ++it) {
        int e = tid + it * 256;
        if (e < 32 * NK) {
            int r = e / NK, q = e - r * NK;
            if (i0 + r < n) {
                size_t o = ((size_t)slice * n + i0 + r) * NK + q;
                ptv[o] = stopv[r][q];
                ptc[o] = stopc[r][q];
            }
        }
    }
}

// ---------------------------------------------------------------------------
// Merge 4 partial top-31 lists -> final top-31 (one wave per row, 124 cands)
// ---------------------------------------------------------------------------
__global__ __launch_bounds__(256) void mergetop(
    const float* __restrict__ pv, const int* __restrict__ pc,
    float* __restrict__ tv, int* __restrict__ tc, int n)
{
    int row = blockIdx.x * 4 + (threadIdx.x >> 6);
    if (row >= n) return;
    int lane = threadIdx.x & 63;
    const int TOT = NSLICE * NK;  // 124
    float v0 = -1e30f, v1 = -1e30f;
    int c0 = 0, c1 = 0;
    int e0 = lane, e1 = lane + 64;
    if (e0 < TOT) {
        int s = e0 / NK, q = e0 - s * NK;
        size_t o = ((size_t)s * n + row) * NK + q;
        v0 = pv[o]; c0 = pc[o];
    }
    if (e1 < TOT) {
        int s = e1 / NK, q = e1 - s * NK;
        size_t o = ((size_t)s * n + row) * NK + q;
        v1 = pv[o]; c1 = pc[o];
    }
    for (int t = 0; t < NK; ++t) {
        float m; int sel;
        if (v1 > v0) { m = v1; sel = 1; } else { m = v0; sel = 0; }
        float bm = m;
        int bid = (lane << 1) | sel;
        #pragma unroll
        for (int off = 1; off < 64; off <<= 1) {
            float om = __shfl_xor(bm, off);
            int oid = __shfl_xor(bid, off);
            if (om > bm || (om == bm && oid < bid)) { bm = om; bid = oid; }
        }
        int wl = bid >> 1;
        int wcol = (bid & 1) ? c1 : c0;
        int wc = __shfl(wcol, wl);
        if (lane == 0) { tv[(size_t)row * NK + t] = bm; tc[(size_t)row * NK + t] = wc; }
        if (lane == wl) { if (bid & 1) v1 = -1e30f; else v0 = -1e30f; }
    }
}

// ---------------------------------------------------------------------------
// norm[i] = sum_j tv[i][j]  +  sum_{e: tc[e]==i} tv[e]   (via reverse CSR)
// ---------------------------------------------------------------------------
__global__ void knorm(const float* __restrict__ tv, const int* __restrict__ offs2,
                      const int* __restrict__ cnt2, const int* __restrict__ eid2,
                      float* __restrict__ nrm, int n)
{
    int i = blockIdx.x * 256 + threadIdx.x;
    if (i >= n) return;
    float s = 0.f;
    for (int j = 0; j < NK; ++j) s += tv[(size_t)i * NK + j];
    int st = offs2[i], en = st + cnt2[i];
    for (int p = st; p < en; ++p) s += tv[eid2[p]];
    nrm[i] = s;
}

// ---------------------------------------------------------------------------
// h_p[row] = (1-t)*[own knn edges + reverse knn edges] + t*[adj edges]
// one wave per row, gather-only, plain store
// ---------------------------------------------------------------------------
__global__ __launch_bounds__(256) void hp_kernel(
    const float* __restrict__ tv, const int* __restrict__ tc,
    const int* __restrict__ offs2, const int* __restrict__ cnt2,
    const int* __restrict__ eid2, const float* __restrict__ nrm,
    const float* __restrict__ ha,
    const int* __restrict__ aoffs, const int* __restrict__ acnt,
    const int* __restrict__ acol, const float* __restrict__ aval,
    const float* __restrict__ tptr, float* __restrict__ hp, int n)
{
    int row = blockIdx.x * 4 + (threadIdx.x >> 6);
    if (row >= n) return;
    int lane = threadIdx.x & 63;
    float t = *tptr;
    float omt = 1.f - t;
    float rni = rsqrtf(nrm[row]);
    float a0 = 0.f, a1 = 0.f, a2 = 0.f, a3 = 0.f;

    // own knn edges (row -> c)
    for (int j = 0; j < NK; ++j) {
        int c = tc[(size_t)row * NK + j];
        float v = tv[(size_t)row * NK + j];
        float w = fmaxf(v * rni * rsqrtf(nrm[c]), 0.f) * omt;
        float4 h = *(const float4*)(ha + (size_t)c * D_H2 + (lane << 2));
        a0 = fmaf(w, h.x, a0); a1 = fmaf(w, h.y, a1);
        a2 = fmaf(w, h.z, a2); a3 = fmaf(w, h.w, a3);
    }
    // reverse knn edges (src -> row, via rev CSR)
    {
        int st = offs2[row], en = st + cnt2[row];
        for (int p = st; p < en; ++p) {
            int e = eid2[p];
            int src = e / NK;
            float v = tv[e];
            float w = fmaxf(v * rsqrtf(nrm[src]) * rni, 0.f) * omt;
            float4 h = *(const float4*)(ha + (size_t)src * D_H2 + (lane << 2));
            a0 = fmaf(w, h.x, a0); a1 = fmaf(w, h.y, a1);
            a2 = fmaf(w, h.z, a2); a3 = fmaf(w, h.w, a3);
        }
    }
    // original adj edges, scaled by t
    {
        int st = aoffs[row], en = st + acnt[row];
        for (int p = st; p < en; ++p) {
            int c = acol[p];
            float w = aval[p] * t;
            float4 h = *(const float4*)(ha + (size_t)c * D_H2 + (lane << 2));
            a0 = fmaf(w, h.x, a0); a1 = fmaf(w, h.y, a1);
            a2 = fmaf(w, h.z, a2); a3 = fmaf(w, h.w, a3);
        }
    }
    float4 o = make_float4(a0, a1, a2, a3);
    *(float4*)(hp + (size_t)row * D_H2 + (lane << 2)) = o;
}

// ---------------------------------------------------------------------------
extern "C" void kernel_launch(void* const* d_in, const int* in_sizes, int n_in,
                              void* d_out, int out_size, void* d_ws, size_t ws_size,
                              hipStream_t stream)
{
    const float* feature = (const float*)d_in[0];
    const int*   arows   = (const int*)d_in[1];
    const int*   acols   = (const int*)d_in[2];
    const float* avals   = (const float*)d_in[3];
    const float* W1      = (const float*)d_in[4];
    const float* b1      = (const float*)d_in[5];
    const float* W2      = (const float*)d_in[6];
    const float* b2      = (const float*)d_in[7];
    const float* tptr    = (const float*)d_in[8];

    float* hs = (float*)d_out;                            // [N, 256]
    float* hp = (float*)d_out + (size_t)N_NODES * D_H2;   // [N, 256]

    char* ws = (char*)d_ws;
    float* h1    = (float*)(ws + 0);           // 20,480,000 B (dead after gemm2)
    float* ptv   = (float*)(ws + 0);           // alias over h1: 4,960,000 B
    int*   ptc   = (int*)  (ws + 4960000);     // 4,960,000 B
    float* ha    = (float*)(ws + 20480000);    // 10,240,000 B
    float* xn    = (float*)(ws + 30720000);    // 10,240,000 B
    float* tv    = (float*)(ws + 40960000);    // 1,240,000 B
    int*   tc    = (int*)  (ws + 42200000);    // 1,240,000 B
    float* nrm   = (float*)(ws + 43440000);    // 40,000 B
    int*   cnt1  = (int*)  (ws + 43480000);
    int*   offs1 = (int*)  (ws + 43520000);
    int*   next1 = (int*)  (ws + 43560000);
    int*   ccol1 = (int*)  (ws + 43600000);    // 1,280,000 B
    float* cval1 = (float*)(ws + 44880000);    // 1,280,000 B
    int*   cnt2  = (int*)  (ws + 46160000);
    int*   offs2 = (int*)  (ws + 46200000);
    int*   next2 = (int*)  (ws + 46240000);
    int*   eid2  = (int*)  (ws + 46280000);    // 1,240,000 B  (total 47.52 MB)

    hipMemsetAsync(cnt1, 0, N_NODES * sizeof(int), stream);
    hipMemsetAsync(cnt2, 0, N_NODES * sizeof(int), stream);

    // MLP
    gemm_bias<<<dim3(D_H1 / 64, (N_NODES + 63) / 64), 256, 0, stream>>>(
        feature, W1, b1, h1, N_NODES, D_H1, D_IN, 1);
    gemm_bias<<<dim3(D_H2 / 64, (N_NODES + 63) / 64), 256, 0, stream>>>(
        h1, W2, b2, hs, N_NODES, D_H2, D_H1, 0);

    // adj CSR + spmm -> ha
    hist_kernel<<<(N_EDGE + 255) / 256, 256, 0, stream>>>(arows, cnt1, N_EDGE);
    scan_kernel<<<1, 256, 0, stream>>>(cnt1, offs1, next1, N_NODES);
    scatter_adj<<<(N_EDGE + 255) / 256, 256, 0, stream>>>(
        arows, acols, avals, next1, ccol1, cval1, N_EDGE);
    spmm_csr<<<(N_NODES + 3) / 4, 256, 0, stream>>>(
        offs1, cnt1, ccol1, cval1, hs, ha, N_NODES);

    // cosine sim + top-k
    rownorm<<<(N_NODES + 3) / 4, 256, 0, stream>>>(ha, xn, N_NODES);
    simtopk<<<dim3((N_NODES + 31) / 32, NSLICE), 256, 0, stream>>>(
        xn, ptv, ptc, N_NODES);
    mergetop<<<(N_NODES + 3) / 4, 256, 0, stream>>>(ptv, ptc, tv, tc, N_NODES);

    // reverse CSR over knn entries
    hist_kernel<<<(N_NODES * NK + 255) / 256, 256, 0, stream>>>(tc, cnt2, N_NODES * NK);
    scan_kernel<<<1, 256, 0, stream>>>(cnt2, offs2, next2, N_NODES);
    scatter_knn<<<(N_NODES * NK + 255) / 256, 256, 0, stream>>>(
        tc, next2, eid2, N_NODES * NK);

    // degree norm + final propagation
    knorm<<<(N_NODES + 255) / 256, 256, 0, stream>>>(tv, offs2, cnt2, eid2, nrm, N_NODES);
    hp_kernel<<<(N_NODES + 3) / 4, 256, 0, stream>>>(
        tv, tc, offs2, cnt2, eid2, nrm, ha, offs1, cnt1, ccol1, cval1, tptr, hp, N_NODES);
}

// Round 2
// 2628.487 us; speedup vs baseline: 1.6710x; 1.6710x over previous
//
#include <hip/hip_runtime.h>
#include <math.h>

#define N_NODES 10000
#define D_IN    512
#define D_H1    512
#define D_H2    256
#define N_EDGE  320000
#define NK      31
#define NSLICE  4
#define JCH     128

typedef short bf16x8 __attribute__((ext_vector_type(8)));
typedef float f32x4  __attribute__((ext_vector_type(4)));

static __device__ __forceinline__ ushort f2bf(float x) {
    uint u = __float_as_uint(x);
    uint r = (u + 0x7fffu + ((u >> 16) & 1u)) >> 16;
    return (ushort)r;
}
static __device__ __forceinline__ float bf2f(ushort h) {
    return __uint_as_float(((uint)h) << 16);
}

// ---------------------------------------------------------------------------
// GEMM: C[M,N] = act(A[M,K] @ B[K,N] + bias), 64x64 tile, 256 thr, 4x4/thread
// ---------------------------------------------------------------------------
__global__ __launch_bounds__(256) void gemm_bias(
    const float* __restrict__ A, const float* __restrict__ B,
    const float* __restrict__ bias, float* __restrict__ C,
    int M, int N, int K, int do_relu)
{
    __shared__ __align__(16) float As[16][68];
    __shared__ __align__(16) float Bs[16][68];
    const int bm = blockIdx.y * 64, bn = blockIdx.x * 64;
    const int tid = threadIdx.x;
    const int tx = tid & 15, ty = tid >> 4;
    const int arow = tid >> 2, akk = (tid & 3) << 2;
    const int bkk = tid >> 4, bnn = (tid & 15) << 2;
    const bool aval = (bm + arow) < M;
    const float* Ap = A + (size_t)(bm + arow) * K;

    float acc[4][4];
    #pragma unroll
    for (int i = 0; i < 4; ++i)
        #pragma unroll
        for (int j = 0; j < 4; ++j) acc[i][j] = 0.f;

    for (int k0 = 0; k0 < K; k0 += 16) {
        float4 av = make_float4(0.f, 0.f, 0.f, 0.f);
        if (aval) av = *(const float4*)(Ap + k0 + akk);
        float4 bv = *(const float4*)(B + (size_t)(k0 + bkk) * N + bn + bnn);
        As[akk + 0][arow] = av.x; As[akk + 1][arow] = av.y;
        As[akk + 2][arow] = av.z; As[akk + 3][arow] = av.w;
        *(float4*)&Bs[bkk][bnn] = bv;
        __syncthreads();
        #pragma unroll
        for (int kk = 0; kk < 16; ++kk) {
            float a[4], b[4];
            *(float4*)a = *(const float4*)&As[kk][ty << 2];
            *(float4*)b = *(const float4*)&Bs[kk][tx << 2];
            #pragma unroll
            for (int i = 0; i < 4; ++i)
                #pragma unroll
                for (int j = 0; j < 4; ++j) acc[i][j] = fmaf(a[i], b[j], acc[i][j]);
        }
        __syncthreads();
    }

    float4 bb = *(const float4*)(bias + bn + (tx << 2));
    float bias4[4] = {bb.x, bb.y, bb.z, bb.w};
    #pragma unroll
    for (int i = 0; i < 4; ++i) {
        int row = bm + (ty << 2) + i;
        if (row < M) {
            float out[4];
            #pragma unroll
            for (int j = 0; j < 4; ++j) {
                float v = acc[i][j] + bias4[j];
                if (do_relu) v = fmaxf(v, 0.f);
                out[j] = v;
            }
            *(float4*)(C + (size_t)row * N + bn + (tx << 2)) = *(float4*)out;
        }
    }
}

// ---------------------------------------------------------------------------
// CSR build helpers
// ---------------------------------------------------------------------------
__global__ void hist_kernel(const int* __restrict__ idx, int* __restrict__ cnt, int n)
{
    int i = blockIdx.x * 256 + threadIdx.x;
    if (i < n) atomicAdd(&cnt[idx[i]], 1);
}

__global__ __launch_bounds__(256) void scan_kernel(
    const int* __restrict__ cnt, int* __restrict__ offs, int* __restrict__ nxt, int n)
{
    __shared__ int ssum[256];
    int t = threadIdx.x;
    int per = (n + 255) >> 8;
    int lo = t * per, hi = min(lo + per, n);
    int s = 0;
    for (int i = lo; i < hi; ++i) s += cnt[i];
    ssum[t] = s;
    __syncthreads();
    if (t == 0) {
        int run = 0;
        for (int i = 0; i < 256; ++i) { int x = ssum[i]; ssum[i] = run; run += x; }
    }
    __syncthreads();
    int run = ssum[t];
    for (int i = lo; i < hi; ++i) { offs[i] = run; nxt[i] = run; run += cnt[i]; }
}

__global__ void scatter_adj(const int* __restrict__ rows, const int* __restrict__ cols,
                            const float* __restrict__ vals, int* __restrict__ nxt,
                            int* __restrict__ ccol, float* __restrict__ cval, int n)
{
    int e = blockIdx.x * 256 + threadIdx.x;
    if (e >= n) return;
    int p = atomicAdd(&nxt[rows[e]], 1);
    ccol[p] = cols[e];
    cval[p] = vals[e];
}

__global__ void scatter_knn(const int* __restrict__ tc, int* __restrict__ nxt,
                            int* __restrict__ eid, int n)
{
    int e = blockIdx.x * 256 + threadIdx.x;
    if (e >= n) return;
    int p = atomicAdd(&nxt[tc[e]], 1);
    eid[p] = e;
}

// ---------------------------------------------------------------------------
// CSR spmm: out[row,:] = sum_e val_e * H[col_e,:]   (one wave per row, D=256)
// ---------------------------------------------------------------------------
__global__ __launch_bounds__(256) void spmm_csr(
    const int* __restrict__ offs, const int* __restrict__ cnt,
    const int* __restrict__ cols, const float* __restrict__ vals,
    const float* __restrict__ H, float* __restrict__ out, int n)
{
    int row = blockIdx.x * 4 + (threadIdx.x >> 6);
    if (row >= n) return;
    int lane = threadIdx.x & 63;
    int st = offs[row], en = st + cnt[row];
    float a0 = 0.f, a1 = 0.f, a2 = 0.f, a3 = 0.f;
    for (int p = st; p < en; ++p) {
        int c = cols[p];
        float v = vals[p];
        float4 h = *(const float4*)(H + (size_t)c * D_H2 + (lane << 2));
        a0 = fmaf(v, h.x, a0); a1 = fmaf(v, h.y, a1);
        a2 = fmaf(v, h.z, a2); a3 = fmaf(v, h.w, a3);
    }
    float4 o = make_float4(a0, a1, a2, a3);
    *(float4*)(out + (size_t)row * D_H2 + (lane << 2)) = o;
}

// ---------------------------------------------------------------------------
// Row L2-normalize + split into bf16 hi/lo: xn = ha/max(||ha||,1e-12)
// hi = bf16(xn), lo = bf16(xn - hi)
// ---------------------------------------------------------------------------
__global__ __launch_bounds__(256) void rownorm_split(
    const float* __restrict__ ha, ushort* __restrict__ xhi,
    ushort* __restrict__ xlo, int n)
{
    int row = blockIdx.x * 4 + (threadIdx.x >> 6);
    if (row >= n) return;
    int lane = threadIdx.x & 63;
    float4 h = *(const float4*)(ha + (size_t)row * D_H2 + (lane << 2));
    float s = h.x * h.x + h.y * h.y + h.z * h.z + h.w * h.w;
    #pragma unroll
    for (int m = 1; m < 64; m <<= 1) s += __shfl_xor(s, m);
    float inv = 1.f / fmaxf(sqrtf(s), 1e-12f);
    float x[4] = {h.x * inv, h.y * inv, h.z * inv, h.w * inv};
    ushort hi[4], lo[4];
    #pragma unroll
    for (int q = 0; q < 4; ++q) {
        hi[q] = f2bf(x[q]);
        lo[q] = f2bf(x[q] - bf2f(hi[q]));
    }
    *(ushort4*)(xhi + (size_t)row * D_H2 + (lane << 2)) =
        make_ushort4(hi[0], hi[1], hi[2], hi[3]);
    *(ushort4*)(xlo + (size_t)row * D_H2 + (lane << 2)) =
        make_ushort4(lo[0], lo[1], lo[2], lo[3]);
}

// ---------------------------------------------------------------------------
// Fused sim-GEMM (bf16 MFMA, hi/lo split) + per-row online top-31.
// Block = 32 i-rows x j-slice. 4 waves: wave w -> i-half (w&1), j-half (w>>1).
// Per j-chunk of 128: each wave computes 4 16x16 MFMA tiles (K=256),
// scores -> LDS -> threshold filter (all 256 thr) -> serial insert (32 thr,
// overlapped with next chunk's MFMA on the other waves).
// ---------------------------------------------------------------------------
__global__ __launch_bounds__(256) void simtopk(
    const ushort* __restrict__ Xhi, const ushort* __restrict__ Xlo,
    float* __restrict__ ptv, int* __restrict__ ptc, int n)
{
    __shared__ float sv[32][132];     // scores; stride 132 -> <=2-way banks
    __shared__ float cbv[32][129];    // candidate values (stride 129: conflict-free column reads)
    __shared__ int   cbc[32][129];    // candidate cols
    __shared__ int   ccnt[32];
    __shared__ float stopv[32][NK];
    __shared__ int   stopc[32][NK];
    __shared__ float sthr[32];
    __shared__ int   scnt[32], smin[32];

    const int i0 = blockIdx.x * 32;
    const int slice = blockIdx.y;
    const int jspan = n / NSLICE;                 // 2500
    const int jbeg = slice * jspan, jend = jbeg + jspan;
    const int tid = threadIdx.x;
    const int w = tid >> 6, lane = tid & 63;
    const int h = w & 1, jq = w >> 1;             // i-half, j-half
    const int l15 = lane & 15, l4 = lane >> 4;

    // Preload this wave's A fragments (16 i-rows, full K=256, hi+lo) into regs.
    int ir = i0 + h * 16 + l15;
    if (ir >= n) ir = n - 1;                      // clamp; results discarded
    const ushort* ah = Xhi + (size_t)ir * D_H2 + l4 * 8;
    const ushort* al = Xlo + (size_t)ir * D_H2 + l4 * 8;
    bf16x8 ahi[8], alo[8];
    #pragma unroll
    for (int ks = 0; ks < 8; ++ks) {
        ahi[ks] = *(const bf16x8*)(ah + ks * 32);
        alo[ks] = *(const bf16x8*)(al + ks * 32);
    }

    if (tid < 32) { sthr[tid] = -1e30f; scnt[tid] = 0; smin[tid] = 0; ccnt[tid] = 0; }
    __syncthreads();

    const int cb = jq * 64 + l15;                 // this lane's base col in chunk

    for (int j0 = jbeg; j0 < jend; j0 += JCH) {
        const int ncol = min(JCH, jend - j0);

        f32x4 acc0 = {0.f, 0.f, 0.f, 0.f};
        f32x4 acc1 = acc0, acc2 = acc0, acc3 = acc0;

        int jr = j0 + jq * 64 + l15;
        size_t b0 = (size_t)min(jr,      n - 1) * D_H2 + l4 * 8;
        size_t b1 = (size_t)min(jr + 16, n - 1) * D_H2 + l4 * 8;
        size_t b2 = (size_t)min(jr + 32, n - 1) * D_H2 + l4 * 8;
        size_t b3 = (size_t)min(jr + 48, n - 1) * D_H2 + l4 * 8;

        #pragma unroll
        for (int ks = 0; ks < 8; ++ks) {
            bf16x8 bh0 = *(const bf16x8*)(Xhi + b0 + ks * 32);
            bf16x8 bl0 = *(const bf16x8*)(Xlo + b0 + ks * 32);
            bf16x8 bh1 = *(const bf16x8*)(Xhi + b1 + ks * 32);
            bf16x8 bl1 = *(const bf16x8*)(Xlo + b1 + ks * 32);
            bf16x8 bh2 = *(const bf16x8*)(Xhi + b2 + ks * 32);
            bf16x8 bl2 = *(const bf16x8*)(Xlo + b2 + ks * 32);
            bf16x8 bh3 = *(const bf16x8*)(Xhi + b3 + ks * 32);
            bf16x8 bl3 = *(const bf16x8*)(Xlo + b3 + ks * 32);
            acc0 = __builtin_amdgcn_mfma_f32_16x16x32_bf16(ahi[ks], bh0, acc0, 0, 0, 0);
            acc1 = __builtin_amdgcn_mfma_f32_16x16x32_bf16(ahi[ks], bh1, acc1, 0, 0, 0);
            acc2 = __builtin_amdgcn_mfma_f32_16x16x32_bf16(ahi[ks], bh2, acc2, 0, 0, 0);
            acc3 = __builtin_amdgcn_mfma_f32_16x16x32_bf16(ahi[ks], bh3, acc3, 0, 0, 0);
            acc0 = __builtin_amdgcn_mfma_f32_16x16x32_bf16(ahi[ks], bl0, acc0, 0, 0, 0);
            acc1 = __builtin_amdgcn_mfma_f32_16x16x32_bf16(ahi[ks], bl1, acc1, 0, 0, 0);
            acc2 = __builtin_amdgcn_mfma_f32_16x16x32_bf16(ahi[ks], bl2, acc2, 0, 0, 0);
            acc3 = __builtin_amdgcn_mfma_f32_16x16x32_bf16(ahi[ks], bl3, acc3, 0, 0, 0);
            acc0 = __builtin_amdgcn_mfma_f32_16x16x32_bf16(alo[ks], bh0, acc0, 0, 0, 0);
            acc1 = __builtin_amdgcn_mfma_f32_16x16x32_bf16(alo[ks], bh1, acc1, 0, 0, 0);
            acc2 = __builtin_amdgcn_mfma_f32_16x16x32_bf16(alo[ks], bh2, acc2, 0, 0, 0);
            acc3 = __builtin_amdgcn_mfma_f32_16x16x32_bf16(alo[ks], bh3, acc3, 0, 0, 0);
        }

        __syncthreads();   // prev chunk's selection done; sv free

        // C/D layout (m89): col = lane&15, row = (lane>>4)*4 + reg
        #pragma unroll
        for (int q = 0; q < 4; ++q) {
            int r = h * 16 + l4 * 4 + q;
            sv[r][cb     ] = (cb      < ncol) ? acc0[q] : -1e30f;
            sv[r][cb + 16] = (cb + 16 < ncol) ? acc1[q] : -1e30f;
            sv[r][cb + 32] = (cb + 32 < ncol) ? acc2[q] : -1e30f;
            sv[r][cb + 48] = (cb + 48 < ncol) ? acc3[q] : -1e30f;
        }
        __syncthreads();

        // threshold filter: 8 threads per row, 16 cols each (stride 8)
        {
            int myrow = tid >> 3, sub = tid & 7;
            float thr = sthr[myrow];
            #pragma unroll
            for (int s = 0; s < 16; ++s) {
                int c = sub + s * 8;
                float v = sv[myrow][c];
                if (v > thr) {
                    int p = atomicAdd(&ccnt[myrow], 1);
                    cbv[myrow][p] = v;
                    cbc[myrow][p] = j0 + c;
                }
            }
        }
        __syncthreads();

        // serial insert of survivors (32 threads; other waves proceed to next MFMA)
        if (tid < 32) {
            int m = ccnt[tid];
            ccnt[tid] = 0;
            int cnt = scnt[tid], mn = smin[tid];
            float thr = sthr[tid];
            for (int p = 0; p < m; ++p) {
                float v = cbv[tid][p];
                int c = cbc[tid][p];
                if (cnt < NK) {
                    stopv[tid][cnt] = v; stopc[tid][cnt] = c; cnt++;
                    if (cnt == NK) {
                        mn = 0; thr = stopv[tid][0];
                        for (int q = 1; q < NK; ++q) {
                            float x = stopv[tid][q];
                            if (x < thr) { thr = x; mn = q; }
                        }
                    }
                } else if (v > thr) {
                    stopv[tid][mn] = v; stopc[tid][mn] = c;
                    mn = 0; thr = stopv[tid][0];
                    for (int q = 1; q < NK; ++q) {
                        float x = stopv[tid][q];
                        if (x < thr) { thr = x; mn = q; }
                    }
                }
            }
            scnt[tid] = cnt; smin[tid] = mn; sthr[tid] = thr;
        }
        // no barrier: next iteration's pre-sv-write barrier orders it
    }

    __syncthreads();
    for (int e = tid; e < 32 * NK; e += 256) {
        int r = e / NK, q = e - r * NK;
        if (i0 + r < n) {
            size_t o = ((size_t)slice * n + i0 + r) * NK + q;
            ptv[o] = stopv[r][q];
            ptc[o] = stopc[r][q];
        }
    }
}

// ---------------------------------------------------------------------------
// Merge 4 partial top-31 lists -> final top-31 (one wave per row, 124 cands)
// ---------------------------------------------------------------------------
__global__ __launch_bounds__(256) void mergetop(
    const float* __restrict__ pv, const int* __restrict__ pc,
    float* __restrict__ tv, int* __restrict__ tc, int n)
{
    int row = blockIdx.x * 4 + (threadIdx.x >> 6);
    if (row >= n) return;
    int lane = threadIdx.x & 63;
    const int TOT = NSLICE * NK;  // 124
    float v0 = -1e30f, v1 = -1e30f;
    int c0 = 0, c1 = 0;
    int e0 = lane, e1 = lane + 64;
    if (e0 < TOT) {
        int s = e0 / NK, q = e0 - s * NK;
        size_t o = ((size_t)s * n + row) * NK + q;
        v0 = pv[o]; c0 = pc[o];
    }
    if (e1 < TOT) {
        int s = e1 / NK, q = e1 - s * NK;
        size_t o = ((size_t)s * n + row) * NK + q;
        v1 = pv[o]; c1 = pc[o];
    }
    for (int t = 0; t < NK; ++t) {
        float m; int sel;
        if (v1 > v0) { m = v1; sel = 1; } else { m = v0; sel = 0; }
        float bm = m;
        int bid = (lane << 1) | sel;
        #pragma unroll
        for (int off = 1; off < 64; off <<= 1) {
            float om = __shfl_xor(bm, off);
            int oid = __shfl_xor(bid, off);
            if (om > bm || (om == bm && oid < bid)) { bm = om; bid = oid; }
        }
        int wl = bid >> 1;
        int wcol = (bid & 1) ? c1 : c0;
        int wc = __shfl(wcol, wl);
        if (lane == 0) { tv[(size_t)row * NK + t] = bm; tc[(size_t)row * NK + t] = wc; }
        if (lane == wl) { if (bid & 1) v1 = -1e30f; else v0 = -1e30f; }
    }
}

// ---------------------------------------------------------------------------
// norm[i] = sum_j tv[i][j]  +  sum_{e: tc[e]==i} tv[e]   (via reverse CSR)
// ---------------------------------------------------------------------------
__global__ void knorm(const float* __restrict__ tv, const int* __restrict__ offs2,
                      const int* __restrict__ cnt2, const int* __restrict__ eid2,
                      float* __restrict__ nrm, int n)
{
    int i = blockIdx.x * 256 + threadIdx.x;
    if (i >= n) return;
    float s = 0.f;
    for (int j = 0; j < NK; ++j) s += tv[(size_t)i * NK + j];
    int st = offs2[i], en = st + cnt2[i];
    for (int p = st; p < en; ++p) s += tv[eid2[p]];
    nrm[i] = s;
}

// ---------------------------------------------------------------------------
// h_p[row] = (1-t)*[own knn edges + reverse knn edges] + t*[adj edges]
// ---------------------------------------------------------------------------
__global__ __launch_bounds__(256) void hp_kernel(
    const float* __restrict__ tv, const int* __restrict__ tc,
    const int* __restrict__ offs2, const int* __restrict__ cnt2,
    const int* __restrict__ eid2, const float* __restrict__ nrm,
    const float* __restrict__ ha,
    const int* __restrict__ aoffs, const int* __restrict__ acnt,
    const int* __restrict__ acol, const float* __restrict__ aval,
    const float* __restrict__ tptr, float* __restrict__ hp, int n)
{
    int row = blockIdx.x * 4 + (threadIdx.x >> 6);
    if (row >= n) return;
    int lane = threadIdx.x & 63;
    float t = *tptr;
    float omt = 1.f - t;
    float rni = rsqrtf(nrm[row]);
    float a0 = 0.f, a1 = 0.f, a2 = 0.f, a3 = 0.f;

    for (int j = 0; j < NK; ++j) {
        int c = tc[(size_t)row * NK + j];
        float v = tv[(size_t)row * NK + j];
        float w = fmaxf(v * rni * rsqrtf(nrm[c]), 0.f) * omt;
        float4 h = *(const float4*)(ha + (size_t)c * D_H2 + (lane << 2));
        a0 = fmaf(w, h.x, a0); a1 = fmaf(w, h.y, a1);
        a2 = fmaf(w, h.z, a2); a3 = fmaf(w, h.w, a3);
    }
    {
        int st = offs2[row], en = st + cnt2[row];
        for (int p = st; p < en; ++p) {
            int e = eid2[p];
            int src = e / NK;
            float v = tv[e];
            float w = fmaxf(v * rsqrtf(nrm[src]) * rni, 0.f) * omt;
            float4 h = *(const float4*)(ha + (size_t)src * D_H2 + (lane << 2));
            a0 = fmaf(w, h.x, a0); a1 = fmaf(w, h.y, a1);
            a2 = fmaf(w, h.z, a2); a3 = fmaf(w, h.w, a3);
        }
    }
    {
        int st = aoffs[row], en = st + acnt[row];
        for (int p = st; p < en; ++p) {
            int c = acol[p];
            float w = aval[p] * t;
            float4 h = *(const float4*)(ha + (size_t)c * D_H2 + (lane << 2));
            a0 = fmaf(w, h.x, a0); a1 = fmaf(w, h.y, a1);
            a2 = fmaf(w, h.z, a2); a3 = fmaf(w, h.w, a3);
        }
    }
    float4 o = make_float4(a0, a1, a2, a3);
    *(float4*)(hp + (size_t)row * D_H2 + (lane << 2)) = o;
}

// ---------------------------------------------------------------------------
extern "C" void kernel_launch(void* const* d_in, const int* in_sizes, int n_in,
                              void* d_out, int out_size, void* d_ws, size_t ws_size,
                              hipStream_t stream)
{
    const float* feature = (const float*)d_in[0];
    const int*   arows   = (const int*)d_in[1];
    const int*   acols   = (const int*)d_in[2];
    const float* avals   = (const float*)d_in[3];
    const float* W1      = (const float*)d_in[4];
    const float* b1      = (const float*)d_in[5];
    const float* W2      = (const float*)d_in[6];
    const float* b2      = (const float*)d_in[7];
    const float* tptr    = (const float*)d_in[8];

    float* hs = (float*)d_out;                            // [N, 256]
    float* hp = (float*)d_out + (size_t)N_NODES * D_H2;   // [N, 256]

    char* ws = (char*)d_ws;
    float*  h1    = (float*) (ws + 0);           // 20,480,000 B (dead after gemm2)
    float*  ptv   = (float*) (ws + 0);           // alias over h1: 4,960,000 B
    int*    ptc   = (int*)   (ws + 4960000);     // 4,960,000 B
    float*  ha    = (float*) (ws + 20480000);    // 10,240,000 B
    ushort* xhi   = (ushort*)(ws + 30720000);    // 5,120,000 B
    ushort* xlo   = (ushort*)(ws + 35840000);    // 5,120,000 B
    float*  tv    = (float*) (ws + 40960000);    // 1,240,000 B
    int*    tc    = (int*)   (ws + 42200000);    // 1,240,000 B
    float*  nrm   = (float*) (ws + 43440000);    // 40,000 B
    int*    cnt1  = (int*)   (ws + 43480000);
    int*    offs1 = (int*)   (ws + 43520000);
    int*    next1 = (int*)   (ws + 43560000);
    int*    ccol1 = (int*)   (ws + 43600000);    // 1,280,000 B
    float*  cval1 = (float*) (ws + 44880000);    // 1,280,000 B
    int*    cnt2  = (int*)   (ws + 46160000);
    int*    offs2 = (int*)   (ws + 46200000);
    int*    next2 = (int*)   (ws + 46240000);
    int*    eid2  = (int*)   (ws + 46280000);    // 1,240,000 B  (total 47.52 MB)

    hipMemsetAsync(cnt1, 0, N_NODES * sizeof(int), stream);
    hipMemsetAsync(cnt2, 0, N_NODES * sizeof(int), stream);

    // MLP
    gemm_bias<<<dim3(D_H1 / 64, (N_NODES + 63) / 64), 256, 0, stream>>>(
        feature, W1, b1, h1, N_NODES, D_H1, D_IN, 1);
    gemm_bias<<<dim3(D_H2 / 64, (N_NODES + 63) / 64), 256, 0, stream>>>(
        h1, W2, b2, hs, N_NODES, D_H2, D_H1, 0);

    // adj CSR + spmm -> ha
    hist_kernel<<<(N_EDGE + 255) / 256, 256, 0, stream>>>(arows, cnt1, N_EDGE);
    scan_kernel<<<1, 256, 0, stream>>>(cnt1, offs1, next1, N_NODES);
    scatter_adj<<<(N_EDGE + 255) / 256, 256, 0, stream>>>(
        arows, acols, avals, next1, ccol1, cval1, N_EDGE);
    spmm_csr<<<(N_NODES + 3) / 4, 256, 0, stream>>>(
        offs1, cnt1, ccol1, cval1, hs, ha, N_NODES);

    // cosine sim (bf16 hi/lo MFMA) + top-k
    rownorm_split<<<(N_NODES + 3) / 4, 256, 0, stream>>>(ha, xhi, xlo, N_NODES);
    simtopk<<<dim3((N_NODES + 31) / 32, NSLICE), 256, 0, stream>>>(
        xhi, xlo, ptv, ptc, N_NODES);
    mergetop<<<(N_NODES + 3) / 4, 256, 0, stream>>>(ptv, ptc, tv, tc, N_NODES);

    // reverse CSR over knn entries
    hist_kernel<<<(N_NODES * NK + 255) / 256, 256, 0, stream>>>(tc, cnt2, N_NODES * NK);
    scan_kernel<<<1, 256, 0, stream>>>(cnt2, offs2, next2, N_NODES);
    scatter_knn<<<(N_NODES * NK + 255) / 256, 256, 0, stream>>>(
        tc, next2, eid2, N_NODES * NK);

    // degree norm + final propagation
    knorm<<<(N_NODES + 255) / 256, 256, 0, stream>>>(tv, offs2, cnt2, eid2, nrm, N_NODES);
    hp_kernel<<<(N_NODES + 3) / 4, 256, 0, stream>>>(
        tv, tc, offs2, cnt2, eid2, nrm, ha, offs1, cnt1, ccol1, cval1, tptr, hp, N_NODES);
}

// Round 3
// 2410.704 us; speedup vs baseline: 1.8220x; 1.0903x over previous
//
#include <hip/hip_runtime.h>
#include <math.h>

#define N_NODES 10000
#define D_IN    512
#define D_H1    512
#define D_H2    256
#define N_EDGE  320000
#define NK      31
#define NSLICE  4
#define CAP     224
#define TRIG    96

typedef short bf16x8 __attribute__((ext_vector_type(8)));
typedef float f32x4  __attribute__((ext_vector_type(4)));

static __device__ __forceinline__ ushort f2bf(float x) {
    uint u = __float_as_uint(x);
    uint r = (u + 0x7fffu + ((u >> 16) & 1u)) >> 16;
    return (ushort)r;
}
static __device__ __forceinline__ float bf2f(ushort h) {
    return __uint_as_float(((uint)h) << 16);
}

// ---------------------------------------------------------------------------
// f32 -> (bf16 hi, bf16 lo) elementwise split (4 elems/thread)
// ---------------------------------------------------------------------------
__global__ __launch_bounds__(256) void split_plain(
    const float* __restrict__ F, ushort* __restrict__ H, ushort* __restrict__ L,
    int nquads)
{
    int q = blockIdx.x * 256 + threadIdx.x;
    if (q >= nquads) return;
    float4 v = *(const float4*)(F + (size_t)q * 4);
    float x[4] = {v.x, v.y, v.z, v.w};
    ushort h[4], l[4];
    #pragma unroll
    for (int j = 0; j < 4; ++j) {
        h[j] = f2bf(x[j]);
        l[j] = f2bf(x[j] - bf2f(h[j]));
    }
    *(ushort4*)(H + (size_t)q * 4) = make_ushort4(h[0], h[1], h[2], h[3]);
    *(ushort4*)(L + (size_t)q * 4) = make_ushort4(l[0], l[1], l[2], l[3]);
}

// ---------------------------------------------------------------------------
// W [K,N] f32 -> Bt [N,K] bf16 hi/lo (transpose + split)
// ---------------------------------------------------------------------------
__global__ __launch_bounds__(256) void split_transpose(
    const float* __restrict__ W, int K, int N,
    ushort* __restrict__ Bh, ushort* __restrict__ Bl)
{
    int q = blockIdx.x * 256 + threadIdx.x;
    int kq4 = K >> 2;
    if (q >= N * kq4) return;
    int nrow = q / kq4, kq = q - nrow * kq4;
    ushort h[4], l[4];
    #pragma unroll
    for (int j = 0; j < 4; ++j) {
        float v = W[(size_t)(kq * 4 + j) * N + nrow];
        h[j] = f2bf(v);
        l[j] = f2bf(v - bf2f(h[j]));
    }
    *(ushort4*)(Bh + (size_t)nrow * K + kq * 4) = make_ushort4(h[0], h[1], h[2], h[3]);
    *(ushort4*)(Bl + (size_t)nrow * K + kq * 4) = make_ushort4(l[0], l[1], l[2], l[3]);
}

// ---------------------------------------------------------------------------
// MFMA GEMM: C[M,N] = act(A @ Bt^T + bias), A/Bt bf16 hi+lo split.
// Block: 32 rows x 128 cols; 4 waves, wave w -> cols w*32..w*32+31 (2 tiles).
// mode 1: relu, write bf16 hi/lo.  mode 0: write f32 C + bf16 Cbf.
// ---------------------------------------------------------------------------
__global__ __launch_bounds__(256) void gemm_mfma(
    const ushort* __restrict__ Ahi, const ushort* __restrict__ Alo,
    const ushort* __restrict__ Bthi, const ushort* __restrict__ Btlo,
    const float* __restrict__ bias, int M, int N, int K, int mode,
    float* __restrict__ C, ushort* __restrict__ Cbf,
    ushort* __restrict__ Chi, ushort* __restrict__ Clo)
{
    const int i0 = blockIdx.x * 32, jb = blockIdx.y * 128;
    const int tid = threadIdx.x, w = tid >> 6, lane = tid & 63;
    const int l15 = lane & 15, l4 = lane >> 4;
    const int ir0 = min(i0 + l15, M - 1), ir1 = min(i0 + 16 + l15, M - 1);
    const int jc = jb + w * 32 + l15;

    const ushort* a0h = Ahi + (size_t)ir0 * K + l4 * 8;
    const ushort* a0l = Alo + (size_t)ir0 * K + l4 * 8;
    const ushort* a1h = Ahi + (size_t)ir1 * K + l4 * 8;
    const ushort* a1l = Alo + (size_t)ir1 * K + l4 * 8;
    const ushort* b0h = Bthi + (size_t)jc * K + l4 * 8;
    const ushort* b0l = Btlo + (size_t)jc * K + l4 * 8;
    const ushort* b1h = Bthi + (size_t)(jc + 16) * K + l4 * 8;
    const ushort* b1l = Btlo + (size_t)(jc + 16) * K + l4 * 8;

    f32x4 acc00 = {0.f, 0.f, 0.f, 0.f};
    f32x4 acc01 = acc00, acc10 = acc00, acc11 = acc00;

    for (int k0 = 0; k0 < K; k0 += 32) {
        bf16x8 Ah0 = *(const bf16x8*)(a0h + k0);
        bf16x8 Al0 = *(const bf16x8*)(a0l + k0);
        bf16x8 Ah1 = *(const bf16x8*)(a1h + k0);
        bf16x8 Al1 = *(const bf16x8*)(a1l + k0);
        bf16x8 Bh0 = *(const bf16x8*)(b0h + k0);
        bf16x8 Bl0 = *(const bf16x8*)(b0l + k0);
        bf16x8 Bh1 = *(const bf16x8*)(b1h + k0);
        bf16x8 Bl1 = *(const bf16x8*)(b1l + k0);
        acc00 = __builtin_amdgcn_mfma_f32_16x16x32_bf16(Ah0, Bh0, acc00, 0, 0, 0);
        acc10 = __builtin_amdgcn_mfma_f32_16x16x32_bf16(Ah1, Bh0, acc10, 0, 0, 0);
        acc01 = __builtin_amdgcn_mfma_f32_16x16x32_bf16(Ah0, Bh1, acc01, 0, 0, 0);
        acc11 = __builtin_amdgcn_mfma_f32_16x16x32_bf16(Ah1, Bh1, acc11, 0, 0, 0);
        acc00 = __builtin_amdgcn_mfma_f32_16x16x32_bf16(Ah0, Bl0, acc00, 0, 0, 0);
        acc10 = __builtin_amdgcn_mfma_f32_16x16x32_bf16(Ah1, Bl0, acc10, 0, 0, 0);
        acc01 = __builtin_amdgcn_mfma_f32_16x16x32_bf16(Ah0, Bl1, acc01, 0, 0, 0);
        acc11 = __builtin_amdgcn_mfma_f32_16x16x32_bf16(Ah1, Bl1, acc11, 0, 0, 0);
        acc00 = __builtin_amdgcn_mfma_f32_16x16x32_bf16(Al0, Bh0, acc00, 0, 0, 0);
        acc10 = __builtin_amdgcn_mfma_f32_16x16x32_bf16(Al1, Bh0, acc10, 0, 0, 0);
        acc01 = __builtin_amdgcn_mfma_f32_16x16x32_bf16(Al0, Bh1, acc01, 0, 0, 0);
        acc11 = __builtin_amdgcn_mfma_f32_16x16x32_bf16(Al1, Bh1, acc11, 0, 0, 0);
    }

    float bs0 = bias[jc], bs1 = bias[jc + 16];
    #pragma unroll
    for (int rt = 0; rt < 2; ++rt) {
        #pragma unroll
        for (int q = 0; q < 4; ++q) {
            int i = i0 + rt * 16 + l4 * 4 + q;
            if (i >= M) continue;
            float v0 = (rt ? acc10[q] : acc00[q]) + bs0;
            float v1 = (rt ? acc11[q] : acc01[q]) + bs1;
            if (mode == 1) {
                v0 = fmaxf(v0, 0.f); v1 = fmaxf(v1, 0.f);
                ushort h0 = f2bf(v0), h1 = f2bf(v1);
                Chi[(size_t)i * N + jc]      = h0;
                Clo[(size_t)i * N + jc]      = f2bf(v0 - bf2f(h0));
                Chi[(size_t)i * N + jc + 16] = h1;
                Clo[(size_t)i * N + jc + 16] = f2bf(v1 - bf2f(h1));
            } else {
                C[(size_t)i * N + jc]        = v0;
                C[(size_t)i * N + jc + 16]   = v1;
                Cbf[(size_t)i * N + jc]      = f2bf(v0);
                Cbf[(size_t)i * N + jc + 16] = f2bf(v1);
            }
        }
    }
}

// ---------------------------------------------------------------------------
// CSR build helpers
// ---------------------------------------------------------------------------
__global__ void hist_kernel(const int* __restrict__ idx, int* __restrict__ cnt, int n)
{
    int i = blockIdx.x * 256 + threadIdx.x;
    if (i < n) atomicAdd(&cnt[idx[i]], 1);
}

__global__ __launch_bounds__(256) void scan_kernel(
    const int* __restrict__ cnt, int* __restrict__ offs, int* __restrict__ nxt, int n)
{
    __shared__ int ssum[256];
    int t = threadIdx.x;
    int per = (n + 255) >> 8;
    int lo = t * per, hi = min(lo + per, n);
    int s = 0;
    for (int i = lo; i < hi; ++i) s += cnt[i];
    ssum[t] = s;
    __syncthreads();
    if (t == 0) {
        int run = 0;
        for (int i = 0; i < 256; ++i) { int x = ssum[i]; ssum[i] = run; run += x; }
    }
    __syncthreads();
    int run = ssum[t];
    for (int i = lo; i < hi; ++i) { offs[i] = run; nxt[i] = run; run += cnt[i]; }
}

__global__ void scatter_adj(const int* __restrict__ rows, const int* __restrict__ cols,
                            const float* __restrict__ vals, int* __restrict__ nxt,
                            int* __restrict__ ccol, float* __restrict__ cval, int n)
{
    int e = blockIdx.x * 256 + threadIdx.x;
    if (e >= n) return;
    int p = atomicAdd(&nxt[rows[e]], 1);
    ccol[p] = cols[e];
    cval[p] = vals[e];
}

__global__ void scatter_knn(const int* __restrict__ tc, int* __restrict__ nxt,
                            int* __restrict__ eid, int n)
{
    int e = blockIdx.x * 256 + threadIdx.x;
    if (e >= n) return;
    int p = atomicAdd(&nxt[tc[e]], 1);
    eid[p] = e;
}

// ---------------------------------------------------------------------------
// CSR spmm over bf16 H: out[row,:] = sum_e val_e * H[col_e,:]  (f32 accum/out)
// ---------------------------------------------------------------------------
__global__ __launch_bounds__(256) void spmm_bf(
    const int* __restrict__ offs, const int* __restrict__ cnt,
    const int* __restrict__ cols, const float* __restrict__ vals,
    const ushort* __restrict__ Hb, float* __restrict__ out, int n)
{
    int row = blockIdx.x * 4 + (threadIdx.x >> 6);
    if (row >= n) return;
    int lane = threadIdx.x & 63;
    int st = offs[row], en = st + cnt[row];
    float a0 = 0.f, a1 = 0.f, a2 = 0.f, a3 = 0.f;
    for (int p = st; p < en; ++p) {
        int c = cols[p];
        float v = vals[p];
        ushort4 h = *(const ushort4*)(Hb + (size_t)c * D_H2 + (lane << 2));
        a0 = fmaf(v, bf2f(h.x), a0); a1 = fmaf(v, bf2f(h.y), a1);
        a2 = fmaf(v, bf2f(h.z), a2); a3 = fmaf(v, bf2f(h.w), a3);
    }
    *(float4*)(out + (size_t)row * D_H2 + (lane << 2)) = make_float4(a0, a1, a2, a3);
}

// ---------------------------------------------------------------------------
// Row L2-normalize + bf16 hi/lo split of Xn + raw-bf16 copy of ha
// ---------------------------------------------------------------------------
__global__ __launch_bounds__(256) void rownorm_split(
    const float* __restrict__ ha, ushort* __restrict__ xhi,
    ushort* __restrict__ xlo, ushort* __restrict__ hab, int n)
{
    int row = blockIdx.x * 4 + (threadIdx.x >> 6);
    if (row >= n) return;
    int lane = threadIdx.x & 63;
    float4 h = *(const float4*)(ha + (size_t)row * D_H2 + (lane << 2));
    *(ushort4*)(hab + (size_t)row * D_H2 + (lane << 2)) =
        make_ushort4(f2bf(h.x), f2bf(h.y), f2bf(h.z), f2bf(h.w));
    float s = h.x * h.x + h.y * h.y + h.z * h.z + h.w * h.w;
    #pragma unroll
    for (int m = 1; m < 64; m <<= 1) s += __shfl_xor(s, m);
    float inv = 1.f / fmaxf(sqrtf(s), 1e-12f);
    float x[4] = {h.x * inv, h.y * inv, h.z * inv, h.w * inv};
    ushort hi[4], lo[4];
    #pragma unroll
    for (int q = 0; q < 4; ++q) {
        hi[q] = f2bf(x[q]);
        lo[q] = f2bf(x[q] - bf2f(hi[q]));
    }
    *(ushort4*)(xhi + (size_t)row * D_H2 + (lane << 2)) =
        make_ushort4(hi[0], hi[1], hi[2], hi[3]);
    *(ushort4*)(xlo + (size_t)row * D_H2 + (lane << 2)) =
        make_ushort4(lo[0], lo[1], lo[2], lo[3]);
}

// ---------------------------------------------------------------------------
// Wave-parallel exact top-31 compaction of a row's candidate buffer.
// Finds the 31st-largest via 32-bit bisection over monotone-encoded floats
// (ballot+popc counting), then gathers survivors in place.
// ---------------------------------------------------------------------------
__device__ __forceinline__ void compact_row(
    float (*bufv)[CAP], int (*bufc)[CAP], int* bcnt, float* thr, int* cpos,
    int r, int lane)
{
    int m = min(bcnt[r], CAP);
    float ev0 = 0.f, ev1 = 0.f, ev2 = 0.f, ev3 = 0.f;
    int   ec0 = 0, ec1 = 0, ec2 = 0, ec3 = 0;
    uint  ue0 = 0u, ue1 = 0u, ue2 = 0u, ue3 = 0u;
    if (lane < m)       { ev0 = bufv[r][lane];       ec0 = bufc[r][lane];       uint u = __float_as_uint(ev0); ue0 = (u >> 31) ? ~u : (u | 0x80000000u); }
    if (lane + 64 < m)  { ev1 = bufv[r][lane + 64];  ec1 = bufc[r][lane + 64];  uint u = __float_as_uint(ev1); ue1 = (u >> 31) ? ~u : (u | 0x80000000u); }
    if (lane + 128 < m) { ev2 = bufv[r][lane + 128]; ec2 = bufc[r][lane + 128]; uint u = __float_as_uint(ev2); ue2 = (u >> 31) ? ~u : (u | 0x80000000u); }
    if (lane + 192 < m) { ev3 = bufv[r][lane + 192]; ec3 = bufc[r][lane + 192]; uint u = __float_as_uint(ev3); ue3 = (u >> 31) ? ~u : (u | 0x80000000u); }

    uint piv = 0u;
    #pragma unroll
    for (int bit = 31; bit >= 0; --bit) {
        uint c = piv | (1u << bit);
        int cntc = __popcll(__ballot(ue0 >= c)) + __popcll(__ballot(ue1 >= c))
                 + __popcll(__ballot(ue2 >= c)) + __popcll(__ballot(ue3 >= c));
        if (cntc >= NK) piv = c;
    }
    if (lane == 0) cpos[r] = 0;
    // same-wave LDS ops are program-ordered: atomics below see the reset
    if (ue0 > piv) { int p = atomicAdd(&cpos[r], 1); bufv[r][p] = ev0; bufc[r][p] = ec0; }
    if (ue1 > piv) { int p = atomicAdd(&cpos[r], 1); bufv[r][p] = ev1; bufc[r][p] = ec1; }
    if (ue2 > piv) { int p = atomicAdd(&cpos[r], 1); bufv[r][p] = ev2; bufc[r][p] = ec2; }
    if (ue3 > piv) { int p = atomicAdd(&cpos[r], 1); bufv[r][p] = ev3; bufc[r][p] = ec3; }
    if (ue0 == piv) { int p = atomicAdd(&cpos[r], 1); if (p < NK) { bufv[r][p] = ev0; bufc[r][p] = ec0; } }
    if (ue1 == piv) { int p = atomicAdd(&cpos[r], 1); if (p < NK) { bufv[r][p] = ev1; bufc[r][p] = ec1; } }
    if (ue2 == piv) { int p = atomicAdd(&cpos[r], 1); if (p < NK) { bufv[r][p] = ev2; bufc[r][p] = ec2; } }
    if (ue3 == piv) { int p = atomicAdd(&cpos[r], 1); if (p < NK) { bufv[r][p] = ev3; bufc[r][p] = ec3; } }
    if (lane == 0) {
        bcnt[r] = NK;
        thr[r] = (piv & 0x80000000u) ? __uint_as_float(piv ^ 0x80000000u)
                                     : __uint_as_float(~piv);
    }
}

// ---------------------------------------------------------------------------
// Fused sim-GEMM (bf16 hi/lo MFMA) + filtered top-31 collection.
// Block = 32 i-rows (A in 128 VGPRs) x 2500-col slice. Wave w owns cols
// w*32..w*32+31 of each 128-chunk -> every B row read once per block.
// Candidates (score > thr) pushed to per-row LDS buffer; rare wave-parallel
// compaction keeps exact top-31.
// ---------------------------------------------------------------------------
__global__ __launch_bounds__(256, 2) void simtopk(
    const ushort* __restrict__ Xhi, const ushort* __restrict__ Xlo,
    float* __restrict__ ptv, int* __restrict__ ptc, int n)
{
    __shared__ float bufv[32][CAP];
    __shared__ int   bufc[32][CAP];
    __shared__ int   bcnt[32];
    __shared__ float thr[32];
    __shared__ int   cpos[32];

    const int i0 = blockIdx.x * 32;
    const int slice = blockIdx.y;
    const int jspan = n / NSLICE;                 // 2500
    const int jbeg = slice * jspan, jend = jbeg + jspan;
    const int tid = threadIdx.x;
    const int w = tid >> 6, lane = tid & 63;
    const int l15 = lane & 15, l4 = lane >> 4;

    // Preload A: all 32 rows (2 row-tiles), full K=256, hi+lo -> 128 VGPRs
    bf16x8 Ahi[2][8], Alo[2][8];
    #pragma unroll
    for (int rt = 0; rt < 2; ++rt) {
        int ir = min(i0 + rt * 16 + l15, n - 1);
        const ushort* ph = Xhi + (size_t)ir * D_H2 + l4 * 8;
        const ushort* pl = Xlo + (size_t)ir * D_H2 + l4 * 8;
        #pragma unroll
        for (int ks = 0; ks < 8; ++ks) {
            Ahi[rt][ks] = *(const bf16x8*)(ph + ks * 32);
            Alo[rt][ks] = *(const bf16x8*)(pl + ks * 32);
        }
    }

    if (tid < 32) { thr[tid] = -1e30f; bcnt[tid] = 0; }
    __syncthreads();

    float tregs[8];
    #pragma unroll
    for (int rt = 0; rt < 2; ++rt)
        #pragma unroll
        for (int q = 0; q < 4; ++q) tregs[rt * 4 + q] = thr[rt * 16 + l4 * 4 + q];

    for (int j0 = jbeg; j0 < jend; j0 += 128) {
        f32x4 acc00 = {0.f, 0.f, 0.f, 0.f};
        f32x4 acc01 = acc00, acc10 = acc00, acc11 = acc00;

        const int jc = j0 + w * 32 + l15;
        const int b0 = min(jc, n - 1) * D_H2 + l4 * 8;
        const int b1 = min(jc + 16, n - 1) * D_H2 + l4 * 8;

        #pragma unroll
        for (int ks = 0; ks < 8; ++ks) {
            bf16x8 bh0 = *(const bf16x8*)(Xhi + b0 + ks * 32);
            bf16x8 bl0 = *(const bf16x8*)(Xlo + b0 + ks * 32);
            bf16x8 bh1 = *(const bf16x8*)(Xhi + b1 + ks * 32);
            bf16x8 bl1 = *(const bf16x8*)(Xlo + b1 + ks * 32);
            acc00 = __builtin_amdgcn_mfma_f32_16x16x32_bf16(Ahi[0][ks], bh0, acc00, 0, 0, 0);
            acc10 = __builtin_amdgcn_mfma_f32_16x16x32_bf16(Ahi[1][ks], bh0, acc10, 0, 0, 0);
            acc01 = __builtin_amdgcn_mfma_f32_16x16x32_bf16(Ahi[0][ks], bh1, acc01, 0, 0, 0);
            acc11 = __builtin_amdgcn_mfma_f32_16x16x32_bf16(Ahi[1][ks], bh1, acc11, 0, 0, 0);
            acc00 = __builtin_amdgcn_mfma_f32_16x16x32_bf16(Ahi[0][ks], bl0, acc00, 0, 0, 0);
            acc10 = __builtin_amdgcn_mfma_f32_16x16x32_bf16(Ahi[1][ks], bl0, acc10, 0, 0, 0);
            acc01 = __builtin_amdgcn_mfma_f32_16x16x32_bf16(Ahi[0][ks], bl1, acc01, 0, 0, 0);
            acc11 = __builtin_amdgcn_mfma_f32_16x16x32_bf16(Ahi[1][ks], bl1, acc11, 0, 0, 0);
            acc00 = __builtin_amdgcn_mfma_f32_16x16x32_bf16(Alo[0][ks], bh0, acc00, 0, 0, 0);
            acc10 = __builtin_amdgcn_mfma_f32_16x16x32_bf16(Alo[1][ks], bh0, acc10, 0, 0, 0);
            acc01 = __builtin_amdgcn_mfma_f32_16x16x32_bf16(Alo[0][ks], bh1, acc01, 0, 0, 0);
            acc11 = __builtin_amdgcn_mfma_f32_16x16x32_bf16(Alo[1][ks], bh1, acc11, 0, 0, 0);
        }

        // fused filter: push survivors (common case: none)
        #pragma unroll
        for (int rt = 0; rt < 2; ++rt) {
            #pragma unroll
            for (int q = 0; q < 4; ++q) {
                int r = rt * 16 + l4 * 4 + q;
                float tq = tregs[rt * 4 + q];
                float v0 = rt ? acc10[q] : acc00[q];
                float v1 = rt ? acc11[q] : acc01[q];
                if (v0 > tq && jc < jend) {
                    int p = atomicAdd(&bcnt[r], 1);
                    if (p < CAP) { bufv[r][p] = v0; bufc[r][p] = jc; }
                }
                if (v1 > tq && jc + 16 < jend) {
                    int p = atomicAdd(&bcnt[r], 1);
                    if (p < CAP) { bufv[r][p] = v1; bufc[r][p] = jc + 16; }
                }
            }
        }
        __syncthreads();

        // compaction: wave w owns rows w*8..w*8+7
        #pragma unroll
        for (int rr = 0; rr < 8; ++rr) {
            int r = w * 8 + rr;
            if (bcnt[r] > TRIG) compact_row(bufv, bufc, bcnt, thr, cpos, r, lane);
        }
        __syncthreads();

        #pragma unroll
        for (int rt = 0; rt < 2; ++rt)
            #pragma unroll
            for (int q = 0; q < 4; ++q) tregs[rt * 4 + q] = thr[rt * 16 + l4 * 4 + q];
    }

    // final exact compaction
    #pragma unroll
    for (int rr = 0; rr < 8; ++rr) {
        int r = w * 8 + rr;
        if (bcnt[r] > NK) compact_row(bufv, bufc, bcnt, thr, cpos, r, lane);
    }
    __syncthreads();

    for (int e = tid; e < 32 * NK; e += 256) {
        int r = e / NK, q = e - r * NK;
        if (i0 + r < n) {
            size_t o = ((size_t)slice * n + i0 + r) * NK + q;
            ptv[o] = bufv[r][q];
            ptc[o] = bufc[r][q];
        }
    }
}

// ---------------------------------------------------------------------------
// Merge 4 partial top-31 lists -> final top-31 (one wave per row, 124 cands)
// ---------------------------------------------------------------------------
__global__ __launch_bounds__(256) void mergetop(
    const float* __restrict__ pv, const int* __restrict__ pc,
    float* __restrict__ tv, int* __restrict__ tc, int n)
{
    int row = blockIdx.x * 4 + (threadIdx.x >> 6);
    if (row >= n) return;
    int lane = threadIdx.x & 63;
    const int TOT = NSLICE * NK;  // 124
    float v0 = -1e30f, v1 = -1e30f;
    int c0 = 0, c1 = 0;
    int e0 = lane, e1 = lane + 64;
    if (e0 < TOT) {
        int s = e0 / NK, q = e0 - s * NK;
        size_t o = ((size_t)s * n + row) * NK + q;
        v0 = pv[o]; c0 = pc[o];
    }
    if (e1 < TOT) {
        int s = e1 / NK, q = e1 - s * NK;
        size_t o = ((size_t)s * n + row) * NK + q;
        v1 = pv[o]; c1 = pc[o];
    }
    for (int t = 0; t < NK; ++t) {
        float m; int sel;
        if (v1 > v0) { m = v1; sel = 1; } else { m = v0; sel = 0; }
        float bm = m;
        int bid = (lane << 1) | sel;
        #pragma unroll
        for (int off = 1; off < 64; off <<= 1) {
            float om = __shfl_xor(bm, off);
            int oid = __shfl_xor(bid, off);
            if (om > bm || (om == bm && oid < bid)) { bm = om; bid = oid; }
        }
        int wl = bid >> 1;
        int wcol = (bid & 1) ? c1 : c0;
        int wc = __shfl(wcol, wl);
        if (lane == 0) { tv[(size_t)row * NK + t] = bm; tc[(size_t)row * NK + t] = wc; }
        if (lane == wl) { if (bid & 1) v1 = -1e30f; else v0 = -1e30f; }
    }
}

// ---------------------------------------------------------------------------
// norm[i] = sum_j tv[i][j] + sum_{e: tc[e]==i} tv[e]  (via reverse CSR)
// ---------------------------------------------------------------------------
__global__ void knorm(const float* __restrict__ tv, const int* __restrict__ offs2,
                      const int* __restrict__ cnt2, const int* __restrict__ eid2,
                      float* __restrict__ nrm, int n)
{
    int i = blockIdx.x * 256 + threadIdx.x;
    if (i >= n) return;
    float s = 0.f;
    for (int j = 0; j < NK; ++j) s += tv[(size_t)i * NK + j];
    int st = offs2[i], en = st + cnt2[i];
    for (int p = st; p < en; ++p) s += tv[eid2[p]];
    nrm[i] = s;
}

// ---------------------------------------------------------------------------
// h_p[row] = (1-t)*[own knn + reverse knn] + t*[adj], bf16 gathers, f32 accum
// ---------------------------------------------------------------------------
__global__ __launch_bounds__(256) void hp_kernel(
    const float* __restrict__ tv, const int* __restrict__ tc,
    const int* __restrict__ offs2, const int* __restrict__ cnt2,
    const int* __restrict__ eid2, const float* __restrict__ nrm,
    const ushort* __restrict__ hab,
    const int* __restrict__ aoffs, const int* __restrict__ acnt,
    const int* __restrict__ acol, const float* __restrict__ aval,
    const float* __restrict__ tptr, float* __restrict__ hp, int n)
{
    int row = blockIdx.x * 4 + (threadIdx.x >> 6);
    if (row >= n) return;
    int lane = threadIdx.x & 63;
    float t = *tptr;
    float omt = 1.f - t;
    float rni = rsqrtf(nrm[row]);
    float a0 = 0.f, a1 = 0.f, a2 = 0.f, a3 = 0.f;

    for (int j = 0; j < NK; ++j) {
        int c = tc[(size_t)row * NK + j];
        float v = tv[(size_t)row * NK + j];
        float wgt = fmaxf(v * rni * rsqrtf(nrm[c]), 0.f) * omt;
        ushort4 h = *(const ushort4*)(hab + (size_t)c * D_H2 + (lane << 2));
        a0 = fmaf(wgt, bf2f(h.x), a0); a1 = fmaf(wgt, bf2f(h.y), a1);
        a2 = fmaf(wgt, bf2f(h.z), a2); a3 = fmaf(wgt, bf2f(h.w), a3);
    }
    {
        int st = offs2[row], en = st + cnt2[row];
        for (int p = st; p < en; ++p) {
            int e = eid2[p];
            int src = e / NK;
            float v = tv[e];
            float wgt = fmaxf(v * rsqrtf(nrm[src]) * rni, 0.f) * omt;
            ushort4 h = *(const ushort4*)(hab + (size_t)src * D_H2 + (lane << 2));
            a0 = fmaf(wgt, bf2f(h.x), a0); a1 = fmaf(wgt, bf2f(h.y), a1);
            a2 = fmaf(wgt, bf2f(h.z), a2); a3 = fmaf(wgt, bf2f(h.w), a3);
        }
    }
    {
        int st = aoffs[row], en = st + acnt[row];
        for (int p = st; p < en; ++p) {
            int c = acol[p];
            float wgt = aval[p] * t;
            ushort4 h = *(const ushort4*)(hab + (size_t)c * D_H2 + (lane << 2));
            a0 = fmaf(wgt, bf2f(h.x), a0); a1 = fmaf(wgt, bf2f(h.y), a1);
            a2 = fmaf(wgt, bf2f(h.z), a2); a3 = fmaf(wgt, bf2f(h.w), a3);
        }
    }
    *(float4*)(hp + (size_t)row * D_H2 + (lane << 2)) = make_float4(a0, a1, a2, a3);
}

// ---------------------------------------------------------------------------
extern "C" void kernel_launch(void* const* d_in, const int* in_sizes, int n_in,
                              void* d_out, int out_size, void* d_ws, size_t ws_size,
                              hipStream_t stream)
{
    const float* feature = (const float*)d_in[0];
    const int*   arows   = (const int*)d_in[1];
    const int*   acols   = (const int*)d_in[2];
    const float* avals   = (const float*)d_in[3];
    const float* W1      = (const float*)d_in[4];
    const float* b1      = (const float*)d_in[5];
    const float* W2      = (const float*)d_in[6];
    const float* b2      = (const float*)d_in[7];
    const float* tptr    = (const float*)d_in[8];

    float* hs = (float*)d_out;                            // [N, 256]
    float* hp = (float*)d_out + (size_t)N_NODES * D_H2;   // [N, 256]

    char* ws = (char*)d_ws;
    // R0 [0, 20.48 MB): fhi/flo (split feature) -> later hsb / xhi / xlo / ptv / ptc
    ushort* fhi  = (ushort*)(ws + 0);            // 10,240,000 B  [split..gemm1]
    ushort* flo  = (ushort*)(ws + 10240000);     // 10,240,000 B  [split..gemm1]
    ushort* xhi  = (ushort*)(ws + 0);            //  5,120,000 B  [rownorm..simtopk]
    ushort* xlo  = (ushort*)(ws + 5120000);      //  5,120,000 B  [rownorm..simtopk]
    ushort* hsb  = (ushort*)(ws + 10240000);     //  5,120,000 B  [gemm2..spmm]
    float*  ptv  = (float*) (ws + 10240000);     //  4,960,000 B  [simtopk..mergetop]
    int*    ptc  = (int*)   (ws + 15200000);     //  4,960,000 B
    // R1 [20.48, 40.96 MB): h1hi/h1lo -> later ha / hab
    ushort* h1hi = (ushort*)(ws + 20480000);     // 10,240,000 B  [gemm1..gemm2]
    ushort* h1lo = (ushort*)(ws + 30720000);     // 10,240,000 B
    float*  ha   = (float*) (ws + 20480000);     // 10,240,000 B  [spmm..hp]
    ushort* hab  = (ushort*)(ws + 30720000);     //  5,120,000 B  [rownorm..hp]
    // R2 small persistent
    float*  tv    = (float*)(ws + 40960000);     // 1,240,000 B
    int*    tc    = (int*)  (ws + 42200000);     // 1,240,000 B
    float*  nrm   = (float*)(ws + 43440000);     // 40,000 B
    int*    cnt1  = (int*)  (ws + 43480000);
    int*    offs1 = (int*)  (ws + 43520000);
    int*    next1 = (int*)  (ws + 43560000);
    int*    ccol1 = (int*)  (ws + 43600000);     // 1,280,000 B
    float*  cval1 = (float*)(ws + 44880000);     // 1,280,000 B
    int*    cnt2  = (int*)  (ws + 46160000);
    int*    offs2 = (int*)  (ws + 46200000);
    int*    next2 = (int*)  (ws + 46240000);
    int*    eid2  = (int*)  (ws + 46280000);     // 1,240,000 B
    ushort* w1thi = (ushort*)(ws + 47520000);    // 524,288 B
    ushort* w1tlo = (ushort*)(ws + 48044288);    // 524,288 B
    ushort* w2thi = (ushort*)(ws + 48568576);    // 262,144 B
    ushort* w2tlo = (ushort*)(ws + 48830720);    // 262,144 B -> 49,092,864 total

    hipMemsetAsync(cnt1, 0, N_NODES * sizeof(int), stream);
    hipMemsetAsync(cnt2, 0, N_NODES * sizeof(int), stream);

    // splits
    split_plain<<<(N_NODES * D_IN / 4 + 255) / 256, 256, 0, stream>>>(
        feature, fhi, flo, N_NODES * D_IN / 4);
    split_transpose<<<(D_H1 * D_IN / 4 + 255) / 256, 256, 0, stream>>>(
        W1, D_IN, D_H1, w1thi, w1tlo);
    split_transpose<<<(D_H2 * D_H1 / 4 + 255) / 256, 256, 0, stream>>>(
        W2, D_H1, D_H2, w2thi, w2tlo);

    // MLP via MFMA
    gemm_mfma<<<dim3((N_NODES + 31) / 32, D_H1 / 128), 256, 0, stream>>>(
        fhi, flo, w1thi, w1tlo, b1, N_NODES, D_H1, D_IN, 1,
        nullptr, nullptr, h1hi, h1lo);
    gemm_mfma<<<dim3((N_NODES + 31) / 32, D_H2 / 128), 256, 0, stream>>>(
        h1hi, h1lo, w2thi, w2tlo, b2, N_NODES, D_H2, D_H1, 0,
        hs, hsb, nullptr, nullptr);

    // adj CSR + spmm -> ha
    hist_kernel<<<(N_EDGE + 255) / 256, 256, 0, stream>>>(arows, cnt1, N_EDGE);
    scan_kernel<<<1, 256, 0, stream>>>(cnt1, offs1, next1, N_NODES);
    scatter_adj<<<(N_EDGE + 255) / 256, 256, 0, stream>>>(
        arows, acols, avals, next1, ccol1, cval1, N_EDGE);
    spmm_bf<<<(N_NODES + 3) / 4, 256, 0, stream>>>(
        offs1, cnt1, ccol1, cval1, hsb, ha, N_NODES);

    // cosine sim + top-k
    rownorm_split<<<(N_NODES + 3) / 4, 256, 0, stream>>>(ha, xhi, xlo, hab, N_NODES);
    simtopk<<<dim3((N_NODES + 31) / 32, NSLICE), 256, 0, stream>>>(
        xhi, xlo, ptv, ptc, N_NODES);
    mergetop<<<(N_NODES + 3) / 4, 256, 0, stream>>>(ptv, ptc, tv, tc, N_NODES);

    // reverse CSR over knn entries
    hist_kernel<<<(N_NODES * NK + 255) / 256, 256, 0, stream>>>(tc, cnt2, N_NODES * NK);
    scan_kernel<<<1, 256, 0, stream>>>(cnt2, offs2, next2, N_NODES);
    scatter_knn<<<(N_NODES * NK + 255) / 256, 256, 0, stream>>>(
        tc, next2, eid2, N_NODES * NK);

    // degree norm + final propagation
    knorm<<<(N_NODES + 255) / 256, 256, 0, stream>>>(tv, offs2, cnt2, eid2, nrm, N_NODES);
    hp_kernel<<<(N_NODES + 3) / 4, 256, 0, stream>>>(
        tv, tc, offs2, cnt2, eid2, nrm, hab, offs1, cnt1, ccol1, cval1, tptr, hp, N_NODES);
}

// Round 4
// 1911.284 us; speedup vs baseline: 2.2981x; 1.2613x over previous
//
#include <hip/hip_runtime.h>
#include <math.h>

#define N_NODES 10000
#define D_IN    512
#define D_H1    512
#define D_H2    256
#define N_EDGE  320000
#define NK      31
#define NSLICE  4
#define CAP     224
#define TRIG    96

typedef short bf16x8 __attribute__((ext_vector_type(8)));
typedef float f32x4  __attribute__((ext_vector_type(4)));

static __device__ __forceinline__ ushort f2bf(float x) {
    uint u = __float_as_uint(x);
    uint r = (u + 0x7fffu + ((u >> 16) & 1u)) >> 16;
    return (ushort)r;
}
static __device__ __forceinline__ float bf2f(ushort h) {
    return __uint_as_float(((uint)h) << 16);
}

// ---------------------------------------------------------------------------
// f32 -> (bf16 hi, bf16 lo) elementwise split (4 elems/thread)
// ---------------------------------------------------------------------------
__global__ __launch_bounds__(256) void split_plain(
    const float* __restrict__ F, ushort* __restrict__ H, ushort* __restrict__ L,
    int nquads)
{
    int q = blockIdx.x * 256 + threadIdx.x;
    if (q >= nquads) return;
    float4 v = *(const float4*)(F + (size_t)q * 4);
    float x[4] = {v.x, v.y, v.z, v.w};
    ushort h[4], l[4];
    #pragma unroll
    for (int j = 0; j < 4; ++j) {
        h[j] = f2bf(x[j]);
        l[j] = f2bf(x[j] - bf2f(h[j]));
    }
    *(ushort4*)(H + (size_t)q * 4) = make_ushort4(h[0], h[1], h[2], h[3]);
    *(ushort4*)(L + (size_t)q * 4) = make_ushort4(l[0], l[1], l[2], l[3]);
}

// ---------------------------------------------------------------------------
// W [K,N] f32 -> Bt [N,K] bf16 hi/lo (transpose + split)
// ---------------------------------------------------------------------------
__global__ __launch_bounds__(256) void split_transpose(
    const float* __restrict__ W, int K, int N,
    ushort* __restrict__ Bh, ushort* __restrict__ Bl)
{
    int q = blockIdx.x * 256 + threadIdx.x;
    int kq4 = K >> 2;
    if (q >= N * kq4) return;
    int nrow = q / kq4, kq = q - nrow * kq4;
    ushort h[4], l[4];
    #pragma unroll
    for (int j = 0; j < 4; ++j) {
        float v = W[(size_t)(kq * 4 + j) * N + nrow];
        h[j] = f2bf(v);
        l[j] = f2bf(v - bf2f(h[j]));
    }
    *(ushort4*)(Bh + (size_t)nrow * K + kq * 4) = make_ushort4(h[0], h[1], h[2], h[3]);
    *(ushort4*)(Bl + (size_t)nrow * K + kq * 4) = make_ushort4(l[0], l[1], l[2], l[3]);
}

// ---------------------------------------------------------------------------
// MFMA GEMM: C[M,N] = act(A @ Bt^T + bias), A/Bt bf16 hi+lo split.
// ---------------------------------------------------------------------------
__global__ __launch_bounds__(256) void gemm_mfma(
    const ushort* __restrict__ Ahi, const ushort* __restrict__ Alo,
    const ushort* __restrict__ Bthi, const ushort* __restrict__ Btlo,
    const float* __restrict__ bias, int M, int N, int K, int mode,
    float* __restrict__ C, ushort* __restrict__ Cbf,
    ushort* __restrict__ Chi, ushort* __restrict__ Clo)
{
    const int i0 = blockIdx.x * 32, jb = blockIdx.y * 128;
    const int tid = threadIdx.x, w = tid >> 6, lane = tid & 63;
    const int l15 = lane & 15, l4 = lane >> 4;
    const int ir0 = min(i0 + l15, M - 1), ir1 = min(i0 + 16 + l15, M - 1);
    const int jc = jb + w * 32 + l15;

    const ushort* a0h = Ahi + (size_t)ir0 * K + l4 * 8;
    const ushort* a0l = Alo + (size_t)ir0 * K + l4 * 8;
    const ushort* a1h = Ahi + (size_t)ir1 * K + l4 * 8;
    const ushort* a1l = Alo + (size_t)ir1 * K + l4 * 8;
    const ushort* b0h = Bthi + (size_t)jc * K + l4 * 8;
    const ushort* b0l = Btlo + (size_t)jc * K + l4 * 8;
    const ushort* b1h = Bthi + (size_t)(jc + 16) * K + l4 * 8;
    const ushort* b1l = Btlo + (size_t)(jc + 16) * K + l4 * 8;

    f32x4 acc00 = {0.f, 0.f, 0.f, 0.f};
    f32x4 acc01 = acc00, acc10 = acc00, acc11 = acc00;

    for (int k0 = 0; k0 < K; k0 += 32) {
        bf16x8 Ah0 = *(const bf16x8*)(a0h + k0);
        bf16x8 Al0 = *(const bf16x8*)(a0l + k0);
        bf16x8 Ah1 = *(const bf16x8*)(a1h + k0);
        bf16x8 Al1 = *(const bf16x8*)(a1l + k0);
        bf16x8 Bh0 = *(const bf16x8*)(b0h + k0);
        bf16x8 Bl0 = *(const bf16x8*)(b0l + k0);
        bf16x8 Bh1 = *(const bf16x8*)(b1h + k0);
        bf16x8 Bl1 = *(const bf16x8*)(b1l + k0);
        acc00 = __builtin_amdgcn_mfma_f32_16x16x32_bf16(Ah0, Bh0, acc00, 0, 0, 0);
        acc10 = __builtin_amdgcn_mfma_f32_16x16x32_bf16(Ah1, Bh0, acc10, 0, 0, 0);
        acc01 = __builtin_amdgcn_mfma_f32_16x16x32_bf16(Ah0, Bh1, acc01, 0, 0, 0);
        acc11 = __builtin_amdgcn_mfma_f32_16x16x32_bf16(Ah1, Bh1, acc11, 0, 0, 0);
        acc00 = __builtin_amdgcn_mfma_f32_16x16x32_bf16(Ah0, Bl0, acc00, 0, 0, 0);
        acc10 = __builtin_amdgcn_mfma_f32_16x16x32_bf16(Ah1, Bl0, acc10, 0, 0, 0);
        acc01 = __builtin_amdgcn_mfma_f32_16x16x32_bf16(Ah0, Bl1, acc01, 0, 0, 0);
        acc11 = __builtin_amdgcn_mfma_f32_16x16x32_bf16(Ah1, Bl1, acc11, 0, 0, 0);
        acc00 = __builtin_amdgcn_mfma_f32_16x16x32_bf16(Al0, Bh0, acc00, 0, 0, 0);
        acc10 = __builtin_amdgcn_mfma_f32_16x16x32_bf16(Al1, Bh0, acc10, 0, 0, 0);
        acc01 = __builtin_amdgcn_mfma_f32_16x16x32_bf16(Al0, Bh1, acc01, 0, 0, 0);
        acc11 = __builtin_amdgcn_mfma_f32_16x16x32_bf16(Al1, Bh1, acc11, 0, 0, 0);
    }

    float bs0 = bias[jc], bs1 = bias[jc + 16];
    #pragma unroll
    for (int rt = 0; rt < 2; ++rt) {
        #pragma unroll
        for (int q = 0; q < 4; ++q) {
            int i = i0 + rt * 16 + l4 * 4 + q;
            if (i >= M) continue;
            float v0 = (rt ? acc10[q] : acc00[q]) + bs0;
            float v1 = (rt ? acc11[q] : acc01[q]) + bs1;
            if (mode == 1) {
                v0 = fmaxf(v0, 0.f); v1 = fmaxf(v1, 0.f);
                ushort h0 = f2bf(v0), h1 = f2bf(v1);
                Chi[(size_t)i * N + jc]      = h0;
                Clo[(size_t)i * N + jc]      = f2bf(v0 - bf2f(h0));
                Chi[(size_t)i * N + jc + 16] = h1;
                Clo[(size_t)i * N + jc + 16] = f2bf(v1 - bf2f(h1));
            } else {
                C[(size_t)i * N + jc]        = v0;
                C[(size_t)i * N + jc + 16]   = v1;
                Cbf[(size_t)i * N + jc]      = f2bf(v0);
                Cbf[(size_t)i * N + jc + 16] = f2bf(v1);
            }
        }
    }
}

// ---------------------------------------------------------------------------
// CSR build helpers
// ---------------------------------------------------------------------------
__global__ void hist_kernel(const int* __restrict__ idx, int* __restrict__ cnt, int n)
{
    int i = blockIdx.x * 256 + threadIdx.x;
    if (i < n) atomicAdd(&cnt[idx[i]], 1);
}

__global__ __launch_bounds__(256) void scan_kernel(
    const int* __restrict__ cnt, int* __restrict__ offs, int* __restrict__ nxt, int n)
{
    __shared__ int ssum[256];
    int t = threadIdx.x;
    int per = (n + 255) >> 8;
    int lo = t * per, hi = min(lo + per, n);
    int s = 0;
    for (int i = lo; i < hi; ++i) s += cnt[i];
    ssum[t] = s;
    __syncthreads();
    if (t == 0) {
        int run = 0;
        for (int i = 0; i < 256; ++i) { int x = ssum[i]; ssum[i] = run; run += x; }
    }
    __syncthreads();
    int run = ssum[t];
    for (int i = lo; i < hi; ++i) { offs[i] = run; nxt[i] = run; run += cnt[i]; }
}

__global__ void scatter_adj(const int* __restrict__ rows, const int* __restrict__ cols,
                            const float* __restrict__ vals, int* __restrict__ nxt,
                            int* __restrict__ ccol, float* __restrict__ cval, int n)
{
    int e = blockIdx.x * 256 + threadIdx.x;
    if (e >= n) return;
    int p = atomicAdd(&nxt[rows[e]], 1);
    ccol[p] = cols[e];
    cval[p] = vals[e];
}

__global__ void scatter_knn(const int* __restrict__ tc, int* __restrict__ nxt,
                            int* __restrict__ eid, int n)
{
    int e = blockIdx.x * 256 + threadIdx.x;
    if (e >= n) return;
    int p = atomicAdd(&nxt[tc[e]], 1);
    eid[p] = e;
}

// ---------------------------------------------------------------------------
// CSR spmm over bf16 H, batched gathers (8 edges in flight per wave)
// ---------------------------------------------------------------------------
__global__ __launch_bounds__(256) void spmm_bf(
    const int* __restrict__ offs, const int* __restrict__ cnt,
    const int* __restrict__ cols, const float* __restrict__ vals,
    const ushort* __restrict__ Hb, float* __restrict__ out, int n)
{
    int row = blockIdx.x * 4 + (threadIdx.x >> 6);
    if (row >= n) return;
    int lane = threadIdx.x & 63;
    int st = offs[row], m = cnt[row];
    float a0 = 0.f, a1 = 0.f, a2 = 0.f, a3 = 0.f;
    for (int p0 = 0; p0 < m; p0 += 8) {
        int c[8]; float v[8];
        #pragma unroll
        for (int jj = 0; jj < 8; ++jj) {
            int p = p0 + jj;
            bool ok = p < m;
            c[jj] = ok ? cols[st + p] : 0;
            v[jj] = ok ? vals[st + p] : 0.f;
        }
        ushort4 hv[8];
        #pragma unroll
        for (int jj = 0; jj < 8; ++jj)
            hv[jj] = *(const ushort4*)(Hb + (size_t)c[jj] * D_H2 + (lane << 2));
        #pragma unroll
        for (int jj = 0; jj < 8; ++jj) {
            a0 = fmaf(v[jj], bf2f(hv[jj].x), a0);
            a1 = fmaf(v[jj], bf2f(hv[jj].y), a1);
            a2 = fmaf(v[jj], bf2f(hv[jj].z), a2);
            a3 = fmaf(v[jj], bf2f(hv[jj].w), a3);
        }
    }
    *(float4*)(out + (size_t)row * D_H2 + (lane << 2)) = make_float4(a0, a1, a2, a3);
}

// ---------------------------------------------------------------------------
// Row L2-normalize + bf16 hi/lo split of Xn + raw-bf16 copy of ha
// ---------------------------------------------------------------------------
__global__ __launch_bounds__(256) void rownorm_split(
    const float* __restrict__ ha, ushort* __restrict__ xhi,
    ushort* __restrict__ xlo, ushort* __restrict__ hab, int n)
{
    int row = blockIdx.x * 4 + (threadIdx.x >> 6);
    if (row >= n) return;
    int lane = threadIdx.x & 63;
    float4 h = *(const float4*)(ha + (size_t)row * D_H2 + (lane << 2));
    *(ushort4*)(hab + (size_t)row * D_H2 + (lane << 2)) =
        make_ushort4(f2bf(h.x), f2bf(h.y), f2bf(h.z), f2bf(h.w));
    float s = h.x * h.x + h.y * h.y + h.z * h.z + h.w * h.w;
    #pragma unroll
    for (int m = 1; m < 64; m <<= 1) s += __shfl_xor(s, m);
    float inv = 1.f / fmaxf(sqrtf(s), 1e-12f);
    float x[4] = {h.x * inv, h.y * inv, h.z * inv, h.w * inv};
    ushort hi[4], lo[4];
    #pragma unroll
    for (int q = 0; q < 4; ++q) {
        hi[q] = f2bf(x[q]);
        lo[q] = f2bf(x[q] - bf2f(hi[q]));
    }
    *(ushort4*)(xhi + (size_t)row * D_H2 + (lane << 2)) =
        make_ushort4(hi[0], hi[1], hi[2], hi[3]);
    *(ushort4*)(xlo + (size_t)row * D_H2 + (lane << 2)) =
        make_ushort4(lo[0], lo[1], lo[2], lo[3]);
}

// ---------------------------------------------------------------------------
// Wave-parallel exact top-31 compaction (bisection over monotone uint codes)
// ---------------------------------------------------------------------------
__device__ __forceinline__ void compact_row(
    float (*bufv)[CAP], int (*bufc)[CAP], int* bcnt, float* thr, int* cpos,
    int r, int lane)
{
    int m = min(bcnt[r], CAP);
    float ev0 = 0.f, ev1 = 0.f, ev2 = 0.f, ev3 = 0.f;
    int   ec0 = 0, ec1 = 0, ec2 = 0, ec3 = 0;
    uint  ue0 = 0u, ue1 = 0u, ue2 = 0u, ue3 = 0u;
    if (lane < m)       { ev0 = bufv[r][lane];       ec0 = bufc[r][lane];       uint u = __float_as_uint(ev0); ue0 = (u >> 31) ? ~u : (u | 0x80000000u); }
    if (lane + 64 < m)  { ev1 = bufv[r][lane + 64];  ec1 = bufc[r][lane + 64];  uint u = __float_as_uint(ev1); ue1 = (u >> 31) ? ~u : (u | 0x80000000u); }
    if (lane + 128 < m) { ev2 = bufv[r][lane + 128]; ec2 = bufc[r][lane + 128]; uint u = __float_as_uint(ev2); ue2 = (u >> 31) ? ~u : (u | 0x80000000u); }
    if (lane + 192 < m) { ev3 = bufv[r][lane + 192]; ec3 = bufc[r][lane + 192]; uint u = __float_as_uint(ev3); ue3 = (u >> 31) ? ~u : (u | 0x80000000u); }

    uint piv = 0u;
    #pragma unroll
    for (int bit = 31; bit >= 0; --bit) {
        uint c = piv | (1u << bit);
        int cntc = __popcll(__ballot(ue0 >= c)) + __popcll(__ballot(ue1 >= c))
                 + __popcll(__ballot(ue2 >= c)) + __popcll(__ballot(ue3 >= c));
        if (cntc >= NK) piv = c;
    }
    if (lane == 0) cpos[r] = 0;
    if (ue0 > piv) { int p = atomicAdd(&cpos[r], 1); bufv[r][p] = ev0; bufc[r][p] = ec0; }
    if (ue1 > piv) { int p = atomicAdd(&cpos[r], 1); bufv[r][p] = ev1; bufc[r][p] = ec1; }
    if (ue2 > piv) { int p = atomicAdd(&cpos[r], 1); bufv[r][p] = ev2; bufc[r][p] = ec2; }
    if (ue3 > piv) { int p = atomicAdd(&cpos[r], 1); bufv[r][p] = ev3; bufc[r][p] = ec3; }
    if (ue0 == piv) { int p = atomicAdd(&cpos[r], 1); if (p < NK) { bufv[r][p] = ev0; bufc[r][p] = ec0; } }
    if (ue1 == piv) { int p = atomicAdd(&cpos[r], 1); if (p < NK) { bufv[r][p] = ev1; bufc[r][p] = ec1; } }
    if (ue2 == piv) { int p = atomicAdd(&cpos[r], 1); if (p < NK) { bufv[r][p] = ev2; bufc[r][p] = ec2; } }
    if (ue3 == piv) { int p = atomicAdd(&cpos[r], 1); if (p < NK) { bufv[r][p] = ev3; bufc[r][p] = ec3; } }
    if (lane == 0) {
        bcnt[r] = NK;
        thr[r] = (piv & 0x80000000u) ? __uint_as_float(piv ^ 0x80000000u)
                                     : __uint_as_float(~piv);
    }
}

// ---------------------------------------------------------------------------
// Fused sim-GEMM (bf16 hi/lo MFMA) + filtered top-31 collection.
// ---------------------------------------------------------------------------
__global__ __launch_bounds__(256, 2) void simtopk(
    const ushort* __restrict__ Xhi, const ushort* __restrict__ Xlo,
    float* __restrict__ ptv, int* __restrict__ ptc, int n)
{
    __shared__ float bufv[32][CAP];
    __shared__ int   bufc[32][CAP];
    __shared__ int   bcnt[32];
    __shared__ float thr[32];
    __shared__ int   cpos[32];

    const int i0 = blockIdx.x * 32;
    const int slice = blockIdx.y;
    const int jspan = n / NSLICE;                 // 2500
    const int jbeg = slice * jspan, jend = jbeg + jspan;
    const int tid = threadIdx.x;
    const int w = tid >> 6, lane = tid & 63;
    const int l15 = lane & 15, l4 = lane >> 4;

    bf16x8 Ahi[2][8], Alo[2][8];
    #pragma unroll
    for (int rt = 0; rt < 2; ++rt) {
        int ir = min(i0 + rt * 16 + l15, n - 1);
        const ushort* ph = Xhi + (size_t)ir * D_H2 + l4 * 8;
        const ushort* pl = Xlo + (size_t)ir * D_H2 + l4 * 8;
        #pragma unroll
        for (int ks = 0; ks < 8; ++ks) {
            Ahi[rt][ks] = *(const bf16x8*)(ph + ks * 32);
            Alo[rt][ks] = *(const bf16x8*)(pl + ks * 32);
        }
    }

    if (tid < 32) { thr[tid] = -1e30f; bcnt[tid] = 0; }
    __syncthreads();

    float tregs[8];
    #pragma unroll
    for (int rt = 0; rt < 2; ++rt)
        #pragma unroll
        for (int q = 0; q < 4; ++q) tregs[rt * 4 + q] = thr[rt * 16 + l4 * 4 + q];

    for (int j0 = jbeg; j0 < jend; j0 += 128) {
        f32x4 acc00 = {0.f, 0.f, 0.f, 0.f};
        f32x4 acc01 = acc00, acc10 = acc00, acc11 = acc00;

        const int jc = j0 + w * 32 + l15;
        const int b0 = min(jc, n - 1) * D_H2 + l4 * 8;
        const int b1 = min(jc + 16, n - 1) * D_H2 + l4 * 8;

        #pragma unroll
        for (int ks = 0; ks < 8; ++ks) {
            bf16x8 bh0 = *(const bf16x8*)(Xhi + b0 + ks * 32);
            bf16x8 bl0 = *(const bf16x8*)(Xlo + b0 + ks * 32);
            bf16x8 bh1 = *(const bf16x8*)(Xhi + b1 + ks * 32);
            bf16x8 bl1 = *(const bf16x8*)(Xlo + b1 + ks * 32);
            acc00 = __builtin_amdgcn_mfma_f32_16x16x32_bf16(Ahi[0][ks], bh0, acc00, 0, 0, 0);
            acc10 = __builtin_amdgcn_mfma_f32_16x16x32_bf16(Ahi[1][ks], bh0, acc10, 0, 0, 0);
            acc01 = __builtin_amdgcn_mfma_f32_16x16x32_bf16(Ahi[0][ks], bh1, acc01, 0, 0, 0);
            acc11 = __builtin_amdgcn_mfma_f32_16x16x32_bf16(Ahi[1][ks], bh1, acc11, 0, 0, 0);
            acc00 = __builtin_amdgcn_mfma_f32_16x16x32_bf16(Ahi[0][ks], bl0, acc00, 0, 0, 0);
            acc10 = __builtin_amdgcn_mfma_f32_16x16x32_bf16(Ahi[1][ks], bl0, acc10, 0, 0, 0);
            acc01 = __builtin_amdgcn_mfma_f32_16x16x32_bf16(Ahi[0][ks], bl1, acc01, 0, 0, 0);
            acc11 = __builtin_amdgcn_mfma_f32_16x16x32_bf16(Ahi[1][ks], bl1, acc11, 0, 0, 0);
            acc00 = __builtin_amdgcn_mfma_f32_16x16x32_bf16(Alo[0][ks], bh0, acc00, 0, 0, 0);
            acc10 = __builtin_amdgcn_mfma_f32_16x16x32_bf16(Alo[1][ks], bh0, acc10, 0, 0, 0);
            acc01 = __builtin_amdgcn_mfma_f32_16x16x32_bf16(Alo[0][ks], bh1, acc01, 0, 0, 0);
            acc11 = __builtin_amdgcn_mfma_f32_16x16x32_bf16(Alo[1][ks], bh1, acc11, 0, 0, 0);
        }

        #pragma unroll
        for (int rt = 0; rt < 2; ++rt) {
            #pragma unroll
            for (int q = 0; q < 4; ++q) {
                int r = rt * 16 + l4 * 4 + q;
                float tq = tregs[rt * 4 + q];
                float v0 = rt ? acc10[q] : acc00[q];
                float v1 = rt ? acc11[q] : acc01[q];
                if (v0 > tq && jc < jend) {
                    int p = atomicAdd(&bcnt[r], 1);
                    if (p < CAP) { bufv[r][p] = v0; bufc[r][p] = jc; }
                }
                if (v1 > tq && jc + 16 < jend) {
                    int p = atomicAdd(&bcnt[r], 1);
                    if (p < CAP) { bufv[r][p] = v1; bufc[r][p] = jc + 16; }
                }
            }
        }
        __syncthreads();

        #pragma unroll
        for (int rr = 0; rr < 8; ++rr) {
            int r = w * 8 + rr;
            if (bcnt[r] > TRIG) compact_row(bufv, bufc, bcnt, thr, cpos, r, lane);
        }
        __syncthreads();

        #pragma unroll
        for (int rt = 0; rt < 2; ++rt)
            #pragma unroll
            for (int q = 0; q < 4; ++q) tregs[rt * 4 + q] = thr[rt * 16 + l4 * 4 + q];
    }

    #pragma unroll
    for (int rr = 0; rr < 8; ++rr) {
        int r = w * 8 + rr;
        if (bcnt[r] > NK) compact_row(bufv, bufc, bcnt, thr, cpos, r, lane);
    }
    __syncthreads();

    for (int e = tid; e < 32 * NK; e += 256) {
        int r = e / NK, q = e - r * NK;
        if (i0 + r < n) {
            size_t o = ((size_t)slice * n + i0 + r) * NK + q;
            ptv[o] = bufv[r][q];
            ptc[o] = bufc[r][q];
        }
    }
}

// ---------------------------------------------------------------------------
// Merge 4 partial top-31 lists -> final top-31 (one wave per row, 124 cands)
// ---------------------------------------------------------------------------
__global__ __launch_bounds__(256) void mergetop(
    const float* __restrict__ pv, const int* __restrict__ pc,
    float* __restrict__ tv, int* __restrict__ tc, int n)
{
    int row = blockIdx.x * 4 + (threadIdx.x >> 6);
    if (row >= n) return;
    int lane = threadIdx.x & 63;
    const int TOT = NSLICE * NK;  // 124
    float v0 = -1e30f, v1 = -1e30f;
    int c0 = 0, c1 = 0;
    int e0 = lane, e1 = lane + 64;
    if (e0 < TOT) {
        int s = e0 / NK, q = e0 - s * NK;
        size_t o = ((size_t)s * n + row) * NK + q;
        v0 = pv[o]; c0 = pc[o];
    }
    if (e1 < TOT) {
        int s = e1 / NK, q = e1 - s * NK;
        size_t o = ((size_t)s * n + row) * NK + q;
        v1 = pv[o]; c1 = pc[o];
    }
    for (int t = 0; t < NK; ++t) {
        float m; int sel;
        if (v1 > v0) { m = v1; sel = 1; } else { m = v0; sel = 0; }
        float bm = m;
        int bid = (lane << 1) | sel;
        #pragma unroll
        for (int off = 1; off < 64; off <<= 1) {
            float om = __shfl_xor(bm, off);
            int oid = __shfl_xor(bid, off);
            if (om > bm || (om == bm && oid < bid)) { bm = om; bid = oid; }
        }
        int wl = bid >> 1;
        int wcol = (bid & 1) ? c1 : c0;
        int wc = __shfl(wcol, wl);
        if (lane == 0) { tv[(size_t)row * NK + t] = bm; tc[(size_t)row * NK + t] = wc; }
        if (lane == wl) { if (bid & 1) v1 = -1e30f; else v0 = -1e30f; }
    }
}

// ---------------------------------------------------------------------------
// rn[i] = rsqrt( sum_j tv[i][j] + sum_{e: tc[e]==i} tv[e] )
// ---------------------------------------------------------------------------
__global__ void knorm(const float* __restrict__ tv, const int* __restrict__ offs2,
                      const int* __restrict__ cnt2, const int* __restrict__ eid2,
                      float* __restrict__ rn, int n)
{
    int i = blockIdx.x * 256 + threadIdx.x;
    if (i >= n) return;
    float s = 0.f;
    for (int j = 0; j < NK; ++j) s += tv[(size_t)i * NK + j];
    int st = offs2[i], en = st + cnt2[i];
    for (int p = st; p < en; ++p) s += tv[eid2[p]];
    rn[i] = rsqrtf(s);
}

// ---------------------------------------------------------------------------
// wk[e] = max(tv[e]*rn[row]*rn[col], 0) * (1-t)   (symmetric edge weight)
// ---------------------------------------------------------------------------
__global__ void knn_weights(const float* __restrict__ tv, const int* __restrict__ tc,
                            const float* __restrict__ rn, const float* __restrict__ tptr,
                            float* __restrict__ wk, int nedge)
{
    int e = blockIdx.x * 256 + threadIdx.x;
    if (e >= nedge) return;
    int row = e / NK;
    int col = tc[e];
    wk[e] = fmaxf(tv[e] * rn[row] * rn[col], 0.f) * (1.f - *tptr);
}

// ---------------------------------------------------------------------------
// h_p[row] = [fwd knn + rev knn with wk] + t*[adj], batched gathers (8 deep)
// ---------------------------------------------------------------------------
__global__ __launch_bounds__(256) void hp_kernel(
    const int* __restrict__ tc, const float* __restrict__ wk,
    const int* __restrict__ offs2, const int* __restrict__ cnt2,
    const int* __restrict__ eid2,
    const ushort* __restrict__ hab,
    const int* __restrict__ aoffs, const int* __restrict__ acnt,
    const int* __restrict__ acol, const float* __restrict__ aval,
    const float* __restrict__ tptr, float* __restrict__ hp, int n)
{
    int row = blockIdx.x * 4 + (threadIdx.x >> 6);
    if (row >= n) return;
    int lane = threadIdx.x & 63;
    float t = *tptr;
    float a0 = 0.f, a1 = 0.f, a2 = 0.f, a3 = 0.f;

    // Phase A: fwd knn edges (affine addresses)
    {
        const int base = row * NK;
        for (int j0 = 0; j0 < NK; j0 += 8) {
            int c[8]; float w[8];
            #pragma unroll
            for (int jj = 0; jj < 8; ++jj) {
                int j = j0 + jj;
                bool ok = j < NK;
                c[jj] = ok ? tc[base + j] : 0;
                w[jj] = ok ? wk[base + j] : 0.f;
            }
            ushort4 hv[8];
            #pragma unroll
            for (int jj = 0; jj < 8; ++jj)
                hv[jj] = *(const ushort4*)(hab + (size_t)c[jj] * D_H2 + (lane << 2));
            #pragma unroll
            for (int jj = 0; jj < 8; ++jj) {
                a0 = fmaf(w[jj], bf2f(hv[jj].x), a0);
                a1 = fmaf(w[jj], bf2f(hv[jj].y), a1);
                a2 = fmaf(w[jj], bf2f(hv[jj].z), a2);
                a3 = fmaf(w[jj], bf2f(hv[jj].w), a3);
            }
        }
    }
    // Phase B: rev knn edges (eid2 -> wk, src = e/NK)
    {
        int st = offs2[row], m = cnt2[row];
        for (int p0 = 0; p0 < m; p0 += 8) {
            int e[8];
            #pragma unroll
            for (int jj = 0; jj < 8; ++jj) {
                int p = p0 + jj;
                e[jj] = (p < m) ? eid2[st + p] : -1;
            }
            int src[8]; float w[8];
            #pragma unroll
            for (int jj = 0; jj < 8; ++jj) {
                if (e[jj] >= 0) { src[jj] = e[jj] / NK; w[jj] = wk[e[jj]]; }
                else            { src[jj] = 0;          w[jj] = 0.f; }
            }
            ushort4 hv[8];
            #pragma unroll
            for (int jj = 0; jj < 8; ++jj)
                hv[jj] = *(const ushort4*)(hab + (size_t)src[jj] * D_H2 + (lane << 2));
            #pragma unroll
            for (int jj = 0; jj < 8; ++jj) {
                a0 = fmaf(w[jj], bf2f(hv[jj].x), a0);
                a1 = fmaf(w[jj], bf2f(hv[jj].y), a1);
                a2 = fmaf(w[jj], bf2f(hv[jj].z), a2);
                a3 = fmaf(w[jj], bf2f(hv[jj].w), a3);
            }
        }
    }
    // Phase C: original adj edges, scaled by t (affine addresses)
    {
        int st = aoffs[row], m = acnt[row];
        for (int p0 = 0; p0 < m; p0 += 8) {
            int c[8]; float w[8];
            #pragma unroll
            for (int jj = 0; jj < 8; ++jj) {
                int p = p0 + jj;
                bool ok = p < m;
                c[jj] = ok ? acol[st + p] : 0;
                w[jj] = ok ? aval[st + p] * t : 0.f;
            }
            ushort4 hv[8];
            #pragma unroll
            for (int jj = 0; jj < 8; ++jj)
                hv[jj] = *(const ushort4*)(hab + (size_t)c[jj] * D_H2 + (lane << 2));
            #pragma unroll
            for (int jj = 0; jj < 8; ++jj) {
                a0 = fmaf(w[jj], bf2f(hv[jj].x), a0);
                a1 = fmaf(w[jj], bf2f(hv[jj].y), a1);
                a2 = fmaf(w[jj], bf2f(hv[jj].z), a2);
                a3 = fmaf(w[jj], bf2f(hv[jj].w), a3);
            }
        }
    }
    *(float4*)(hp + (size_t)row * D_H2 + (lane << 2)) = make_float4(a0, a1, a2, a3);
}

// ---------------------------------------------------------------------------
extern "C" void kernel_launch(void* const* d_in, const int* in_sizes, int n_in,
                              void* d_out, int out_size, void* d_ws, size_t ws_size,
                              hipStream_t stream)
{
    const float* feature = (const float*)d_in[0];
    const int*   arows   = (const int*)d_in[1];
    const int*   acols   = (const int*)d_in[2];
    const float* avals   = (const float*)d_in[3];
    const float* W1      = (const float*)d_in[4];
    const float* b1      = (const float*)d_in[5];
    const float* W2      = (const float*)d_in[6];
    const float* b2      = (const float*)d_in[7];
    const float* tptr    = (const float*)d_in[8];

    float* hs = (float*)d_out;                            // [N, 256]
    float* hp = (float*)d_out + (size_t)N_NODES * D_H2;   // [N, 256]

    char* ws = (char*)d_ws;
    // R0 [0, 20.48 MB): fhi/flo -> later xhi/xlo (dead after simtopk) -> wk
    ushort* fhi  = (ushort*)(ws + 0);            // [split..gemm1]
    ushort* flo  = (ushort*)(ws + 10240000);     // [split..gemm1]
    ushort* xhi  = (ushort*)(ws + 0);            // [rownorm..simtopk]
    ushort* xlo  = (ushort*)(ws + 5120000);      // [rownorm..simtopk]
    float*  wk   = (float*) (ws + 0);            // 1,240,000 B [knn_weights..hp]
    ushort* hsb  = (ushort*)(ws + 10240000);     // [gemm2..spmm]
    float*  ptv  = (float*) (ws + 10240000);     // [simtopk..mergetop]
    int*    ptc  = (int*)   (ws + 15200000);
    // R1 [20.48, 40.96 MB): h1hi/h1lo -> later ha / hab
    ushort* h1hi = (ushort*)(ws + 20480000);     // [gemm1..gemm2]
    ushort* h1lo = (ushort*)(ws + 30720000);
    float*  ha   = (float*) (ws + 20480000);     // [spmm..rownorm]
    ushort* hab  = (ushort*)(ws + 30720000);     // [rownorm..hp]
    // R2 small persistent
    float*  tv    = (float*)(ws + 40960000);     // 1,240,000 B
    int*    tc    = (int*)  (ws + 42200000);     // 1,240,000 B
    float*  rn    = (float*)(ws + 43440000);     // 40,000 B
    int*    cnt1  = (int*)  (ws + 43480000);
    int*    offs1 = (int*)  (ws + 43520000);
    int*    next1 = (int*)  (ws + 43560000);
    int*    ccol1 = (int*)  (ws + 43600000);     // 1,280,000 B
    float*  cval1 = (float*)(ws + 44880000);     // 1,280,000 B
    int*    cnt2  = (int*)  (ws + 46160000);
    int*    offs2 = (int*)  (ws + 46200000);
    int*    next2 = (int*)  (ws + 46240000);
    int*    eid2  = (int*)  (ws + 46280000);     // 1,240,000 B
    ushort* w1thi = (ushort*)(ws + 47520000);    // 524,288 B
    ushort* w1tlo = (ushort*)(ws + 48044288);    // 524,288 B
    ushort* w2thi = (ushort*)(ws + 48568576);    // 262,144 B
    ushort* w2tlo = (ushort*)(ws + 48830720);    // 262,144 B -> 49,092,864 total

    hipMemsetAsync(cnt1, 0, N_NODES * sizeof(int), stream);
    hipMemsetAsync(cnt2, 0, N_NODES * sizeof(int), stream);

    // splits
    split_plain<<<(N_NODES * D_IN / 4 + 255) / 256, 256, 0, stream>>>(
        feature, fhi, flo, N_NODES * D_IN / 4);
    split_transpose<<<(D_H1 * D_IN / 4 + 255) / 256, 256, 0, stream>>>(
        W1, D_IN, D_H1, w1thi, w1tlo);
    split_transpose<<<(D_H2 * D_H1 / 4 + 255) / 256, 256, 0, stream>>>(
        W2, D_H1, D_H2, w2thi, w2tlo);

    // MLP via MFMA
    gemm_mfma<<<dim3((N_NODES + 31) / 32, D_H1 / 128), 256, 0, stream>>>(
        fhi, flo, w1thi, w1tlo, b1, N_NODES, D_H1, D_IN, 1,
        nullptr, nullptr, h1hi, h1lo);
    gemm_mfma<<<dim3((N_NODES + 31) / 32, D_H2 / 128), 256, 0, stream>>>(
        h1hi, h1lo, w2thi, w2tlo, b2, N_NODES, D_H2, D_H1, 0,
        hs, hsb, nullptr, nullptr);

    // adj CSR + spmm -> ha
    hist_kernel<<<(N_EDGE + 255) / 256, 256, 0, stream>>>(arows, cnt1, N_EDGE);
    scan_kernel<<<1, 256, 0, stream>>>(cnt1, offs1, next1, N_NODES);
    scatter_adj<<<(N_EDGE + 255) / 256, 256, 0, stream>>>(
        arows, acols, avals, next1, ccol1, cval1, N_EDGE);
    spmm_bf<<<(N_NODES + 3) / 4, 256, 0, stream>>>(
        offs1, cnt1, ccol1, cval1, hsb, ha, N_NODES);

    // cosine sim + top-k
    rownorm_split<<<(N_NODES + 3) / 4, 256, 0, stream>>>(ha, xhi, xlo, hab, N_NODES);
    simtopk<<<dim3((N_NODES + 31) / 32, NSLICE), 256, 0, stream>>>(
        xhi, xlo, ptv, ptc, N_NODES);
    mergetop<<<(N_NODES + 3) / 4, 256, 0, stream>>>(ptv, ptc, tv, tc, N_NODES);

    // reverse CSR over knn entries
    hist_kernel<<<(N_NODES * NK + 255) / 256, 256, 0, stream>>>(tc, cnt2, N_NODES * NK);
    scan_kernel<<<1, 256, 0, stream>>>(cnt2, offs2, next2, N_NODES);
    scatter_knn<<<(N_NODES * NK + 255) / 256, 256, 0, stream>>>(
        tc, next2, eid2, N_NODES * NK);

    // degree norm (rsqrt), symmetric edge weights, final propagation
    knorm<<<(N_NODES + 255) / 256, 256, 0, stream>>>(tv, offs2, cnt2, eid2, rn, N_NODES);
    knn_weights<<<(N_NODES * NK + 255) / 256, 256, 0, stream>>>(
        tv, tc, rn, tptr, wk, N_NODES * NK);
    hp_kernel<<<(N_NODES + 3) / 4, 256, 0, stream>>>(
        tc, wk, offs2, cnt2, eid2, hab, offs1, cnt1, ccol1, cval1, tptr, hp, N_NODES);
}